// Round 5
// baseline (1237.715 us; speedup 1.0000x reference)
//
#include <hip/hip_runtime.h>
#include <hip/hip_bf16.h>

typedef __attribute__((ext_vector_type(8))) short short8;
typedef __attribute__((ext_vector_type(4))) float f32x4;

#define T_STEPS 48
#define BATCH 32
#define EDIM 512
#define HDIM 1024
#define VOCAB 32000
#define GRU_BLOCKS 128
#define JPB 8

__device__ __forceinline__ unsigned short f2bf(float f) {
    __hip_bfloat16 h = __float2bfloat16(f);
    return *reinterpret_cast<unsigned short*>(&h);
}
__device__ __forceinline__ float bf2f(unsigned short u) {
    union { unsigned int i; float f; } v;
    v.i = ((unsigned int)u) << 16;
    return v.f;
}

// global -> LDS async copy, 16B per lane (wave-uniform LDS base).
typedef __attribute__((address_space(1))) const void GAS;
typedef __attribute__((address_space(3))) void LAS;
__device__ __forceinline__ void gload_lds16(const unsigned short* g, unsigned short* l) {
    __builtin_amdgcn_global_load_lds((GAS*)g, (LAS*)(unsigned)(uintptr_t)l, 16, 0, 0);
}

// ---------------- prep: all fp32->bf16 conversions + embedding gather ----------------
__global__ __launch_bounds__(256) void prep_kernel(
    const float* __restrict__ h0, const int* __restrict__ tseq,
    const float* __restrict__ emb, const float* __restrict__ w_ih,
    const float* __restrict__ w_hh, const float* __restrict__ w_cls,
    unsigned short* __restrict__ wcls_bf, unsigned short* __restrict__ wih_bf,
    unsigned short* __restrict__ whh_hi, unsigned short* __restrict__ whh_lo,
    unsigned short* __restrict__ x_bf, unsigned short* __restrict__ hs_hi,
    unsigned short* __restrict__ hs_lo)
{
    const long R0 = (long)VOCAB * HDIM / 4;
    const long R1 = (long)3 * HDIM * EDIM / 4;
    const long R2 = (long)3 * HDIM * HDIM / 4;
    const long R3 = (long)T_STEPS * BATCH * EDIM / 4;
    const long R4 = (long)BATCH * HDIM / 4;
    const long total = R0 + R1 + R2 + R3 + R4;

    for (long i = (long)blockIdx.x * blockDim.x + threadIdx.x; i < total;
         i += (long)gridDim.x * blockDim.x) {
        if (i < R0) {
            float4 v = reinterpret_cast<const float4*>(w_cls)[i];
            ushort4 u = { f2bf(v.x), f2bf(v.y), f2bf(v.z), f2bf(v.w) };
            *reinterpret_cast<ushort4*>(wcls_bf + i * 4) = u;
        } else if (i < R0 + R1) {
            long j = i - R0;
            float4 v = reinterpret_cast<const float4*>(w_ih)[j];
            ushort4 u = { f2bf(v.x), f2bf(v.y), f2bf(v.z), f2bf(v.w) };
            *reinterpret_cast<ushort4*>(wih_bf + j * 4) = u;
        } else if (i < R0 + R1 + R2) {
            long j = i - R0 - R1;
            float4 v = reinterpret_cast<const float4*>(w_hh)[j];
            ushort4 hi = { f2bf(v.x), f2bf(v.y), f2bf(v.z), f2bf(v.w) };
            ushort4 lo = { f2bf(v.x - bf2f(hi.x)), f2bf(v.y - bf2f(hi.y)),
                           f2bf(v.z - bf2f(hi.z)), f2bf(v.w - bf2f(hi.w)) };
            *reinterpret_cast<ushort4*>(whh_hi + j * 4) = hi;
            *reinterpret_cast<ushort4*>(whh_lo + j * 4) = lo;
        } else if (i < R0 + R1 + R2 + R3) {
            long j = i - R0 - R1 - R2;
            int m = (int)(j >> 7);
            int kk4 = (int)(j & 127);
            int t = m >> 5, b = m & 31;
            int tok = tseq[b * T_STEPS + t];
            float4 v = reinterpret_cast<const float4*>(emb)[(long)tok * (EDIM / 4) + kk4];
            ushort4 u = { f2bf(v.x), f2bf(v.y), f2bf(v.z), f2bf(v.w) };
            *reinterpret_cast<ushort4*>(x_bf + (long)m * EDIM + kk4 * 4) = u;
        } else {
            long j = i - R0 - R1 - R2 - R3;
            float4 v = reinterpret_cast<const float4*>(h0)[j];
            ushort4 hi = { f2bf(v.x), f2bf(v.y), f2bf(v.z), f2bf(v.w) };
            ushort4 lo = { f2bf(v.x - bf2f(hi.x)), f2bf(v.y - bf2f(hi.y)),
                           f2bf(v.z - bf2f(hi.z)), f2bf(v.w - bf2f(hi.w)) };
            *reinterpret_cast<ushort4*>(hs_hi + j * 4) = hi;
            *reinterpret_cast<ushort4*>(hs_lo + j * 4) = lo;
        }
    }
}

// ---------------- bf16 MFMA GEMM (gload_lds staging, XCD swizzle) ----------------
template <bool SCORES>
__global__ __launch_bounds__(256) void gemm_lds(
    const unsigned short* __restrict__ A, const unsigned short* __restrict__ B,
    const float* __restrict__ bias, float* __restrict__ C, int K, int Ntot, int nM)
{
    const int nwg = gridDim.x;
    const int lin = blockIdx.x;
    const int q = nwg >> 3;
    const int wg = (lin & 7) * q + (lin >> 3);
    const int mi = wg % nM, ni = wg / nM;
    const int m0 = mi * 128, n0 = ni * 128;

    const int tid = threadIdx.x;
    const int lane = tid & 63;
    const int wid = tid >> 6;
    const int wr = wid >> 1, wc = wid & 1;

    __shared__ __align__(16) unsigned short As[128 * 32];
    __shared__ __align__(16) unsigned short Bs[128 * 32];

    f32x4 acc[4][4] = {};
    const int NT = K >> 5;
    const int srow = (lane >> 2);
    const int skk = (lane & 3) * 8;

    for (int kt = 0; kt < NT; ++kt) {
        __syncthreads();
        {
            const int kb = kt * 32;
#pragma unroll
            for (int h2 = 0; h2 < 2; ++h2) {
                const int i = wid + h2 * 4;
                const int row = i * 16 + srow;
                gload_lds16(A + (size_t)(m0 + row) * K + kb + skk, As + i * 512);
                gload_lds16(B + (size_t)(n0 + row) * K + kb + skk, Bs + i * 512);
            }
        }
        __syncthreads();

        const int kg = lane >> 4;
        const int l15 = lane & 15;
        short8 af[4], bf[4];
#pragma unroll
        for (int i = 0; i < 4; ++i) {
            af[i] = *(const short8*)(As + ((wr * 64 + i * 16 + l15) * 32 + kg * 8));
            bf[i] = *(const short8*)(Bs + ((wc * 64 + i * 16 + l15) * 32 + kg * 8));
        }
#pragma unroll
        for (int i = 0; i < 4; ++i)
#pragma unroll
            for (int j = 0; j < 4; ++j)
                acc[i][j] = __builtin_amdgcn_mfma_f32_16x16x32_bf16(af[i], bf[j], acc[i][j], 0, 0, 0);
    }

    const int l15 = lane & 15, lhi = lane >> 4;
#pragma unroll
    for (int i = 0; i < 4; ++i) {
#pragma unroll
        for (int j = 0; j < 4; ++j) {
            int col = n0 + wc * 64 + j * 16 + l15;
            float bv = bias[col];
#pragma unroll
            for (int q2 = 0; q2 < 4; ++q2) {
                int row = m0 + wr * 64 + i * 16 + lhi * 4 + q2;
                float v = acc[i][j][q2] + bv;
                if (SCORES) {
                    int t = row >> 5, b = row & 31;
                    C[(size_t)(b * T_STEPS + t) * Ntot + col] = v;
                } else {
                    C[(size_t)row * Ntot + col] = v;
                }
            }
        }
    }
}

// ---------------- persistent GRU: W_hh lives in LDS for all 48 steps ----------------
// 128 blocks x 256 threads (4 waves). Block owns 8 j-columns x 3 gates = 24 W rows.
// LDS: W hi+lo [2][32][1032] (132KB, rows 24..31 zero), filled once -> immune to
// the per-step acquire invalidation. Per step only h is re-read from memory.
__global__ __launch_bounds__(256, 1) void gru_persist(
    unsigned short* __restrict__ hs_hi, unsigned short* __restrict__ hs_lo,
    const unsigned short* __restrict__ whh_hi, const unsigned short* __restrict__ whh_lo,
    const float* __restrict__ gi, const float* __restrict__ b_hh, int* __restrict__ bar)
{
    const int j0 = blockIdx.x * JPB;
    const int tid = threadIdx.x;
    const int lane = tid & 63, wid = tid >> 6;     // 4 waves
    const int l15 = lane & 15, kg = lane >> 4;     // kg 0..3
    const int kq = wid * 256;                      // wave's K-chunk

    __shared__ __align__(16) unsigned short Wl[2][32][1032];  // [hi/lo][row][k] 132KB
    __shared__ float P[4][32][25];
    __shared__ float Hloc[BATCH][JPB];
    __shared__ float Bh[24];

    // ---- one-time LDS fill: 24 real W rows (g*8+jj), rows 24..31 zero ----
    for (int c = tid; c < 32 * 128; c += 256) {
        int row = c >> 7, k8 = (c & 127) * 8;
        short8 vh = {0, 0, 0, 0, 0, 0, 0, 0};
        short8 vl = {0, 0, 0, 0, 0, 0, 0, 0};
        if (row < 24) {
            int g = row >> 3, jj = row & 7;
            size_t off = (size_t)(g * HDIM + j0 + jj) * HDIM + k8;
            vh = *(const short8*)(whh_hi + off);
            vl = *(const short8*)(whh_lo + off);
        }
        *(short8*)&Wl[0][row][k8] = vh;
        *(short8*)&Wl[1][row][k8] = vl;
    }
    if (tid < 24) Bh[tid] = b_hh[(tid >> 3) * HDIM + j0 + (tid & 7)];
    {
        int b = tid >> 3, jj = tid & 7;
        size_t o = (size_t)b * HDIM + j0 + jj;
        Hloc[b][jj] = bf2f(hs_hi[o]) + bf2f(hs_lo[o]);
    }
    __syncthreads();

    for (int t = 0; t < T_STEPS; ++t) {
        const unsigned short* hA_hi = hs_hi + (size_t)t * BATCH * HDIM;
        const unsigned short* hA_lo = hs_lo + (size_t)t * BATCH * HDIM;

        // all 32 h-loads issued upfront: one latency exposure
        short8 ah[8][2], al[8][2];
#pragma unroll
        for (int ks = 0; ks < 8; ++ks) {
            const int kb = kq + ks * 32 + kg * 8;
#pragma unroll
            for (int mi = 0; mi < 2; ++mi) {
                const size_t off = (size_t)(mi * 16 + l15) * HDIM + kb;
                ah[ks][mi] = *(const short8*)(hA_hi + off);
                al[ks][mi] = *(const short8*)(hA_lo + off);
            }
        }

        f32x4 acc[2][2] = {};    // [mi][fr]
#pragma unroll
        for (int ks = 0; ks < 8; ++ks) {
            const int kb = kq + ks * 32 + kg * 8;
#pragma unroll
            for (int fr = 0; fr < 2; ++fr) {
                short8 bhi = *(const short8*)&Wl[0][fr * 16 + l15][kb];
                short8 blo = *(const short8*)&Wl[1][fr * 16 + l15][kb];
#pragma unroll
                for (int mi = 0; mi < 2; ++mi) {
                    acc[mi][fr] = __builtin_amdgcn_mfma_f32_16x16x32_bf16(ah[ks][mi], bhi, acc[mi][fr], 0, 0, 0);
                    acc[mi][fr] = __builtin_amdgcn_mfma_f32_16x16x32_bf16(ah[ks][mi], blo, acc[mi][fr], 0, 0, 0);
                    acc[mi][fr] = __builtin_amdgcn_mfma_f32_16x16x32_bf16(al[ks][mi], bhi, acc[mi][fr], 0, 0, 0);
                }
            }
        }

        // scatter partials: C/D map col(l15)=W-row, row(kg*4+q)=batch
#pragma unroll
        for (int mi = 0; mi < 2; ++mi)
#pragma unroll
            for (int fr = 0; fr < 2; ++fr)
                if (fr == 0 || l15 < 8)
#pragma unroll
                    for (int q = 0; q < 4; ++q)
                        P[wid][mi * 16 + kg * 4 + q][fr * 16 + l15] = acc[mi][fr][q];
        __syncthreads();

        {
            int b = tid >> 3, jj = tid & 7;
            float ghr = 0.f, ghz = 0.f, ghn = 0.f;
#pragma unroll
            for (int w = 0; w < 4; ++w) {
                ghr += P[w][b][jj];
                ghz += P[w][b][8 + jj];
                ghn += P[w][b][16 + jj];
            }
            ghr += Bh[jj];
            ghz += Bh[8 + jj];
            ghn += Bh[16 + jj];
            const int j = j0 + jj;
            const float* girow = gi + (size_t)(t * BATCH + b) * (3 * HDIM);
            float xr = girow[j], xz = girow[HDIM + j], xn = girow[2 * HDIM + j];
            float r = 1.f / (1.f + __expf(-(xr + ghr)));
            float z = 1.f / (1.f + __expf(-(xz + ghz)));
            float n = tanhf(xn + r * ghn);
            float hnew = (1.f - z) * n + z * Hloc[b][jj];
            Hloc[b][jj] = hnew;
            unsigned short hi = f2bf(hnew);
            unsigned short lo = f2bf(hnew - bf2f(hi));
            const size_t o = (size_t)(t + 1) * BATCH * HDIM + (size_t)b * HDIM + j;
            hs_hi[o] = hi;
            hs_lo[o] = lo;
        }

        // ---- grid barrier ----
        __threadfence();
        __syncthreads();
        if (tid == 0) {
            int v = __hip_atomic_fetch_add(bar, 1, __ATOMIC_ACQ_REL, __HIP_MEMORY_SCOPE_AGENT);
            if (v == GRU_BLOCKS * (t + 1) - 1) {
                __hip_atomic_store(bar + 1, t + 1, __ATOMIC_RELEASE, __HIP_MEMORY_SCOPE_AGENT);
            } else {
                while (__hip_atomic_load(bar + 1, __ATOMIC_RELAXED, __HIP_MEMORY_SCOPE_AGENT) < t + 1)
                    __builtin_amdgcn_s_sleep(1);
                (void)__hip_atomic_load(bar + 1, __ATOMIC_ACQUIRE, __HIP_MEMORY_SCOPE_AGENT);
            }
        }
        __syncthreads();
    }
}

extern "C" void kernel_launch(void* const* d_in, const int* in_sizes, int n_in,
                              void* d_out, int out_size, void* d_ws, size_t ws_size,
                              hipStream_t stream) {
    const float* h0    = (const float*)d_in[0];
    const int*   tseq  = (const int*)d_in[1];
    const float* emb   = (const float*)d_in[2];
    const float* w_ih  = (const float*)d_in[3];
    const float* w_hh  = (const float*)d_in[4];
    const float* b_ih  = (const float*)d_in[5];
    const float* b_hh  = (const float*)d_in[6];
    const float* w_cls = (const float*)d_in[7];
    const float* b_cls = (const float*)d_in[8];
    float* out = (float*)d_out;

    char* w = (char*)d_ws;
    unsigned short* wcls_bf = (unsigned short*)w; w += (size_t)VOCAB * HDIM * 2;
    unsigned short* wih_bf  = (unsigned short*)w; w += (size_t)3 * HDIM * EDIM * 2;
    unsigned short* whh_hi  = (unsigned short*)w; w += (size_t)3 * HDIM * HDIM * 2;
    unsigned short* whh_lo  = (unsigned short*)w; w += (size_t)3 * HDIM * HDIM * 2;
    unsigned short* x_bf    = (unsigned short*)w; w += (size_t)T_STEPS * BATCH * EDIM * 2;
    unsigned short* hs_hi   = (unsigned short*)w; w += (size_t)(T_STEPS + 1) * BATCH * HDIM * 2;
    unsigned short* hs_lo   = (unsigned short*)w; w += (size_t)(T_STEPS + 1) * BATCH * HDIM * 2;
    float* gi               = (float*)w;          w += (size_t)T_STEPS * BATCH * 3 * HDIM * 4;
    int* bar                = (int*)w;            w += 256;

    hipMemsetAsync(bar, 0, 8, stream);

    prep_kernel<<<2048, 256, 0, stream>>>(h0, tseq, emb, w_ih, w_hh, w_cls,
                                          wcls_bf, wih_bf, whh_hi, whh_lo,
                                          x_bf, hs_hi, hs_lo);

    // GI = X @ W_ih^T + b_ih : M=1536, N=3072, K=512  (288 wgs, %8==0)
    gemm_lds<false><<<(T_STEPS * BATCH / 128) * (3 * HDIM / 128), 256, 0, stream>>>(
        x_bf, wih_bf, b_ih, gi, EDIM, 3 * HDIM, T_STEPS * BATCH / 128);

    // all 48 GRU steps in one persistent launch (W_hh in LDS)
    gru_persist<<<GRU_BLOCKS, 256, 0, stream>>>(hs_hi, hs_lo, whh_hi, whh_lo, gi, b_hh, bar);

    // scores = Hs[1..48] @ W_cls^T + b_cls : M=1536, N=32000, K=1024 (3000 wgs, %8==0)
    gemm_lds<true><<<(T_STEPS * BATCH / 128) * (VOCAB / 128), 256, 0, stream>>>(
        hs_hi + (size_t)BATCH * HDIM, wcls_bf, b_cls, out, HDIM, VOCAB, T_STEPS * BATCH / 128);
}

// Round 6
// 1164.785 us; speedup vs baseline: 1.0626x; 1.0626x over previous
//
#include <hip/hip_runtime.h>
#include <hip/hip_bf16.h>

typedef __attribute__((ext_vector_type(8))) short short8;
typedef __attribute__((ext_vector_type(4))) float f32x4;

#define T_STEPS 48
#define BATCH 32
#define EDIM 512
#define HDIM 1024
#define VOCAB 32000
#define GRU_BLOCKS 128
#define JPB 8
#define SENT 0x7FFF7FFFu

// packed h storage: uint words, [t(49)][plane(2: hi,lo)][b(32)][word(512)]
#define HS_T_STRIDE 32768          // uints per t-slot
#define HS_PLANE 16384             // uints per plane

__device__ __forceinline__ unsigned short f2bf(float f) {
    __hip_bfloat16 h = __float2bfloat16(f);
    return *reinterpret_cast<unsigned short*>(&h);
}
__device__ __forceinline__ float bf2f(unsigned short u) {
    union { unsigned int i; float f; } v;
    v.i = ((unsigned int)u) << 16;
    return v.f;
}

typedef __attribute__((address_space(1))) const void GAS;
typedef __attribute__((address_space(3))) void LAS;
__device__ __forceinline__ void gload_lds16(const unsigned short* g, unsigned short* l) {
    __builtin_amdgcn_global_load_lds((GAS*)g, (LAS*)(unsigned)(uintptr_t)l, 16, 0, 0);
}

// ---------------- prep: fp32->bf16 conversions, gather, h0 pack, sentinel fill ----------------
__global__ __launch_bounds__(256) void prep_kernel(
    const float* __restrict__ h0, const int* __restrict__ tseq,
    const float* __restrict__ emb, const float* __restrict__ w_ih,
    const float* __restrict__ w_hh, const float* __restrict__ w_cls,
    unsigned short* __restrict__ wcls_bf, unsigned short* __restrict__ wih_bf,
    unsigned short* __restrict__ whh_hi, unsigned short* __restrict__ whh_lo,
    unsigned short* __restrict__ x_bf, unsigned int* __restrict__ hs32)
{
    const long R0 = (long)VOCAB * HDIM / 4;           // w_cls
    const long R1 = (long)3 * HDIM * EDIM / 4;        // w_ih
    const long R2 = (long)3 * HDIM * HDIM / 4;        // w_hh hi+lo
    const long R3 = (long)T_STEPS * BATCH * EDIM / 4; // X gather
    const long R4 = (long)BATCH * HDIM / 2;           // h0 -> packed slot 0 (words)
    const long R5 = (long)T_STEPS * HS_T_STRIDE / 4;  // sentinel fill t=1..48 (uint4)
    const long total = R0 + R1 + R2 + R3 + R4 + R5;

    for (long i = (long)blockIdx.x * blockDim.x + threadIdx.x; i < total;
         i += (long)gridDim.x * blockDim.x) {
        if (i < R0) {
            float4 v = reinterpret_cast<const float4*>(w_cls)[i];
            ushort4 u = { f2bf(v.x), f2bf(v.y), f2bf(v.z), f2bf(v.w) };
            *reinterpret_cast<ushort4*>(wcls_bf + i * 4) = u;
        } else if (i < R0 + R1) {
            long j = i - R0;
            float4 v = reinterpret_cast<const float4*>(w_ih)[j];
            ushort4 u = { f2bf(v.x), f2bf(v.y), f2bf(v.z), f2bf(v.w) };
            *reinterpret_cast<ushort4*>(wih_bf + j * 4) = u;
        } else if (i < R0 + R1 + R2) {
            long j = i - R0 - R1;
            float4 v = reinterpret_cast<const float4*>(w_hh)[j];
            ushort4 hi = { f2bf(v.x), f2bf(v.y), f2bf(v.z), f2bf(v.w) };
            ushort4 lo = { f2bf(v.x - bf2f(hi.x)), f2bf(v.y - bf2f(hi.y)),
                           f2bf(v.z - bf2f(hi.z)), f2bf(v.w - bf2f(hi.w)) };
            *reinterpret_cast<ushort4*>(whh_hi + j * 4) = hi;
            *reinterpret_cast<ushort4*>(whh_lo + j * 4) = lo;
        } else if (i < R0 + R1 + R2 + R3) {
            long j = i - R0 - R1 - R2;
            int m = (int)(j >> 7);
            int kk4 = (int)(j & 127);
            int t = m >> 5, b = m & 31;
            int tok = tseq[b * T_STEPS + t];
            float4 v = reinterpret_cast<const float4*>(emb)[(long)tok * (EDIM / 4) + kk4];
            ushort4 u = { f2bf(v.x), f2bf(v.y), f2bf(v.z), f2bf(v.w) };
            *reinterpret_cast<ushort4*>(x_bf + (long)m * EDIM + kk4 * 4) = u;
        } else if (i < R0 + R1 + R2 + R3 + R4) {
            long j = i - R0 - R1 - R2 - R3;
            int b = (int)(j >> 9), wp = (int)(j & 511);
            float f0 = h0[b * HDIM + 2 * wp];
            float f1 = h0[b * HDIM + 2 * wp + 1];
            unsigned short h0a = f2bf(f0), h1a = f2bf(f1);
            unsigned short l0 = f2bf(f0 - bf2f(h0a)), l1 = f2bf(f1 - bf2f(h1a));
            hs32[(size_t)b * 512 + wp] = (unsigned)h0a | ((unsigned)h1a << 16);
            hs32[HS_PLANE + (size_t)b * 512 + wp] = (unsigned)l0 | ((unsigned)l1 << 16);
        } else {
            long j = i - R0 - R1 - R2 - R3 - R4;
            uint4 s = { SENT, SENT, SENT, SENT };
            reinterpret_cast<uint4*>(hs32 + HS_T_STRIDE)[j] = s;   // t=1..48, both planes
        }
    }
}

// ---------------- bf16 MFMA GEMM (gload_lds staging, XCD swizzle) ----------------
// SCORES=false: A[M][K] rows contiguous. SCORES=true: A row m lives in packed
// hs32 hi-plane at t=(m>>5)+1, b=m&31 (1024 contiguous bf16-hi per row).
template <bool SCORES>
__global__ __launch_bounds__(256) void gemm_lds(
    const unsigned short* __restrict__ A, const unsigned short* __restrict__ B,
    const float* __restrict__ bias, float* __restrict__ C, int K, int Ntot, int nM)
{
    const int nwg = gridDim.x;
    const int lin = blockIdx.x;
    const int q = nwg >> 3;
    const int wg = (lin & 7) * q + (lin >> 3);
    const int mi = wg % nM, ni = wg / nM;
    const int m0 = mi * 128, n0 = ni * 128;

    const int tid = threadIdx.x;
    const int lane = tid & 63;
    const int wid = tid >> 6;
    const int wr = wid >> 1, wc = wid & 1;

    __shared__ __align__(16) unsigned short As[128 * 32];
    __shared__ __align__(16) unsigned short Bs[128 * 32];

    f32x4 acc[4][4] = {};
    const int NT = K >> 5;
    const int srow = (lane >> 2);
    const int skk = (lane & 3) * 8;

    for (int kt = 0; kt < NT; ++kt) {
        __syncthreads();
        {
            const int kb = kt * 32;
#pragma unroll
            for (int h2 = 0; h2 < 2; ++h2) {
                const int i = wid + h2 * 4;
                const int row = i * 16 + srow;
                const int m = m0 + row;
                size_t aoff;
                if (SCORES)
                    aoff = (size_t)((m >> 5) + 1) * (2 * HS_T_STRIDE) + (size_t)(m & 31) * 1024 + kb + skk;
                else
                    aoff = (size_t)m * K + kb + skk;
                gload_lds16(A + aoff, As + i * 512);
                gload_lds16(B + (size_t)(n0 + row) * K + kb + skk, Bs + i * 512);
            }
        }
        __syncthreads();

        const int kg = lane >> 4;
        const int l15 = lane & 15;
        short8 af[4], bf[4];
#pragma unroll
        for (int i = 0; i < 4; ++i) {
            af[i] = *(const short8*)(As + ((wr * 64 + i * 16 + l15) * 32 + kg * 8));
            bf[i] = *(const short8*)(Bs + ((wc * 64 + i * 16 + l15) * 32 + kg * 8));
        }
#pragma unroll
        for (int i = 0; i < 4; ++i)
#pragma unroll
            for (int j = 0; j < 4; ++j)
                acc[i][j] = __builtin_amdgcn_mfma_f32_16x16x32_bf16(af[i], bf[j], acc[i][j], 0, 0, 0);
    }

    const int l15 = lane & 15, lhi = lane >> 4;
#pragma unroll
    for (int i = 0; i < 4; ++i) {
#pragma unroll
        for (int j = 0; j < 4; ++j) {
            int col = n0 + wc * 64 + j * 16 + l15;
            float bv = bias[col];
#pragma unroll
            for (int q2 = 0; q2 < 4; ++q2) {
                int row = m0 + wr * 64 + i * 16 + lhi * 4 + q2;
                float v = acc[i][j][q2] + bv;
                if (SCORES) {
                    int t = row >> 5, b = row & 31;
                    C[(size_t)(b * T_STEPS + t) * Ntot + col] = v;
                } else {
                    C[(size_t)row * Ntot + col] = v;
                }
            }
        }
    }
}

// ---------------- persistent GRU: fence-free dataflow pipeline ----------------
// 128 blocks x 256 threads. W_hh in LDS (filled once). h communicated through
// MALL via relaxed agent atomics on packed (2x bf16) words; sentinel spin gives
// per-word dataflow sync. NO fences, NO barriers, NO atomic RMW anywhere.
__global__ __launch_bounds__(256, 1) void gru_persist(
    unsigned int* __restrict__ hs32,
    const unsigned short* __restrict__ whh_hi, const unsigned short* __restrict__ whh_lo,
    const float* __restrict__ gi, const float* __restrict__ b_hh)
{
    const int j0 = blockIdx.x * JPB;
    const int tid = threadIdx.x;
    const int lane = tid & 63, wid = tid >> 6;     // 4 waves
    const int l15 = lane & 15, kg = lane >> 4;     // kg 0..3
    const int kq = wid * 256;                      // wave's K-chunk (ushort units)

    __shared__ __align__(16) unsigned short Wl[2][32][1032];  // 132KB, rows 24..31 zero
    __shared__ float P[4][32][25];
    __shared__ float Hloc[BATCH][JPB];
    __shared__ unsigned short Hsh[BATCH][JPB];
    __shared__ unsigned short Hsl[BATCH][JPB];
    __shared__ float Bh[24];

    // one-time W fill (normal cached loads; read-only data stays cached all kernel)
    for (int c = tid; c < 32 * 128; c += 256) {
        int row = c >> 7, k8 = (c & 127) * 8;
        short8 vh = {0, 0, 0, 0, 0, 0, 0, 0};
        short8 vl = {0, 0, 0, 0, 0, 0, 0, 0};
        if (row < 24) {
            int g = row >> 3, jj = row & 7;
            size_t off = (size_t)(g * HDIM + j0 + jj) * HDIM + k8;
            vh = *(const short8*)(whh_hi + off);
            vl = *(const short8*)(whh_lo + off);
        }
        *(short8*)&Wl[0][row][k8] = vh;
        *(short8*)&Wl[1][row][k8] = vl;
    }
    if (tid < 24) Bh[tid] = b_hh[(tid >> 3) * HDIM + j0 + (tid & 7)];
    {
        int b = tid >> 3, jj = tid & 7;
        unsigned w0 = __hip_atomic_load(hs32 + (size_t)b * 512 + ((j0 + jj) >> 1),
                                        __ATOMIC_RELAXED, __HIP_MEMORY_SCOPE_AGENT);
        unsigned w1 = __hip_atomic_load(hs32 + HS_PLANE + (size_t)b * 512 + ((j0 + jj) >> 1),
                                        __ATOMIC_RELAXED, __HIP_MEMORY_SCOPE_AGENT);
        unsigned short hi = (jj & 1) ? (unsigned short)(w0 >> 16) : (unsigned short)(w0 & 0xffff);
        unsigned short lo = (jj & 1) ? (unsigned short)(w1 >> 16) : (unsigned short)(w1 & 0xffff);
        Hloc[b][jj] = bf2f(hi) + bf2f(lo);
    }
    __syncthreads();

    for (int t = 0; t < T_STEPS; ++t) {
        const unsigned tb = (unsigned)t * HS_T_STRIDE;

        // gi prefetch for this step (normal cached loads, overlap with h wait)
        const int gb = tid >> 3, gjj = tid & 7;
        const int gj = j0 + gjj;
        const float* girow = gi + (size_t)(t * BATCH + gb) * (3 * HDIM);
        float xr = girow[gj], xz = girow[HDIM + gj], xn = girow[2 * HDIM + gj];

        // burst-load all 128 h-words (hi+lo planes), then sentinel-spin
        unsigned wv[8][16];
#pragma unroll
        for (int ks = 0; ks < 8; ++ks) {
            const unsigned base = tb + (unsigned)(wid * 128 + ks * 16 + kg * 4);
#pragma unroll
            for (int mi = 0; mi < 2; ++mi) {
                const unsigned ro = (unsigned)(mi * 16 + l15) * 512 + base;
#pragma unroll
                for (int q = 0; q < 4; ++q) {
                    wv[ks][mi * 4 + q] = __hip_atomic_load(hs32 + ro + q,
                        __ATOMIC_RELAXED, __HIP_MEMORY_SCOPE_AGENT);
                    wv[ks][8 + mi * 4 + q] = __hip_atomic_load(hs32 + HS_PLANE + ro + q,
                        __ATOMIC_RELAXED, __HIP_MEMORY_SCOPE_AGENT);
                }
            }
        }
#pragma unroll
        for (int ks = 0; ks < 8; ++ks)
#pragma unroll
            for (int i = 0; i < 16; ++i) {
                while (__builtin_expect(wv[ks][i] == SENT, 0)) {
                    __builtin_amdgcn_s_sleep(1);
                    const int mi = (i & 7) >> 2, q = i & 3, pl = i >> 3;
                    wv[ks][i] = __hip_atomic_load(
                        hs32 + (unsigned)pl * HS_PLANE + (unsigned)(mi * 16 + l15) * 512 +
                            tb + (unsigned)(wid * 128 + ks * 16 + kg * 4) + q,
                        __ATOMIC_RELAXED, __HIP_MEMORY_SCOPE_AGENT);
                }
            }

        // MFMA: acc[mi][fr] over 8 K-slices, bf16x3
        f32x4 acc[2][2] = {};
#pragma unroll
        for (int ks = 0; ks < 8; ++ks) {
            const int kb = kq + ks * 32 + kg * 8;
            union U8 { unsigned u[4]; short8 s; };
            short8 ah[2], al[2];
#pragma unroll
            for (int mi = 0; mi < 2; ++mi) {
                U8 x, y;
#pragma unroll
                for (int q = 0; q < 4; ++q) { x.u[q] = wv[ks][mi * 4 + q]; y.u[q] = wv[ks][8 + mi * 4 + q]; }
                ah[mi] = x.s; al[mi] = y.s;
            }
#pragma unroll
            for (int fr = 0; fr < 2; ++fr) {
                short8 bhi = *(const short8*)&Wl[0][fr * 16 + l15][kb];
                short8 blo = *(const short8*)&Wl[1][fr * 16 + l15][kb];
#pragma unroll
                for (int mi = 0; mi < 2; ++mi) {
                    acc[mi][fr] = __builtin_amdgcn_mfma_f32_16x16x32_bf16(ah[mi], bhi, acc[mi][fr], 0, 0, 0);
                    acc[mi][fr] = __builtin_amdgcn_mfma_f32_16x16x32_bf16(ah[mi], blo, acc[mi][fr], 0, 0, 0);
                    acc[mi][fr] = __builtin_amdgcn_mfma_f32_16x16x32_bf16(al[mi], bhi, acc[mi][fr], 0, 0, 0);
                }
            }
        }

        // scatter partials: C/D map col(l15)=W-row, row(kg*4+q)=batch
#pragma unroll
        for (int mi = 0; mi < 2; ++mi)
#pragma unroll
            for (int fr = 0; fr < 2; ++fr)
                if (fr == 0 || l15 < 8)
#pragma unroll
                    for (int q = 0; q < 4; ++q)
                        P[wid][mi * 16 + kg * 4 + q][fr * 16 + l15] = acc[mi][fr][q];
        __syncthreads();

        // gates (one (b,jj) per thread)
        {
            float ghr = 0.f, ghz = 0.f, ghn = 0.f;
#pragma unroll
            for (int w = 0; w < 4; ++w) {
                ghr += P[w][gb][gjj];
                ghz += P[w][gb][8 + gjj];
                ghn += P[w][gb][16 + gjj];
            }
            ghr += Bh[gjj];
            ghz += Bh[8 + gjj];
            ghn += Bh[16 + gjj];
            float r = 1.f / (1.f + __expf(-(xr + ghr)));
            float z = 1.f / (1.f + __expf(-(xz + ghz)));
            float n = tanhf(xn + r * ghn);
            float hnew = (1.f - z) * n + z * Hloc[gb][gjj];
            Hloc[gb][gjj] = hnew;
            unsigned short hi = f2bf(hnew);
            Hsh[gb][gjj] = hi;
            Hsl[gb][gjj] = f2bf(hnew - bf2f(hi));
        }
        __syncthreads();

        // pack + publish (relaxed write-through; no fence)
        if (tid < 128) {
            int b = tid >> 2, p = tid & 3;
            unsigned hw = (unsigned)Hsh[b][2 * p] | ((unsigned)Hsh[b][2 * p + 1] << 16);
            unsigned lw = (unsigned)Hsl[b][2 * p] | ((unsigned)Hsl[b][2 * p + 1] << 16);
            size_t o = (size_t)(t + 1) * HS_T_STRIDE + (size_t)b * 512 + (j0 >> 1) + p;
            __hip_atomic_store(hs32 + o, hw, __ATOMIC_RELAXED, __HIP_MEMORY_SCOPE_AGENT);
            __hip_atomic_store(hs32 + o + HS_PLANE, lw, __ATOMIC_RELAXED, __HIP_MEMORY_SCOPE_AGENT);
        }
        __syncthreads();   // protect P/Hsh reuse next iteration
    }
}

extern "C" void kernel_launch(void* const* d_in, const int* in_sizes, int n_in,
                              void* d_out, int out_size, void* d_ws, size_t ws_size,
                              hipStream_t stream) {
    const float* h0    = (const float*)d_in[0];
    const int*   tseq  = (const int*)d_in[1];
    const float* emb   = (const float*)d_in[2];
    const float* w_ih  = (const float*)d_in[3];
    const float* w_hh  = (const float*)d_in[4];
    const float* b_ih  = (const float*)d_in[5];
    const float* b_hh  = (const float*)d_in[6];
    const float* w_cls = (const float*)d_in[7];
    const float* b_cls = (const float*)d_in[8];
    float* out = (float*)d_out;

    char* w = (char*)d_ws;
    unsigned short* wcls_bf = (unsigned short*)w; w += (size_t)VOCAB * HDIM * 2;
    unsigned short* wih_bf  = (unsigned short*)w; w += (size_t)3 * HDIM * EDIM * 2;
    unsigned short* whh_hi  = (unsigned short*)w; w += (size_t)3 * HDIM * HDIM * 2;
    unsigned short* whh_lo  = (unsigned short*)w; w += (size_t)3 * HDIM * HDIM * 2;
    unsigned short* x_bf    = (unsigned short*)w; w += (size_t)T_STEPS * BATCH * EDIM * 2;
    unsigned int*   hs32    = (unsigned int*)w;   w += (size_t)(T_STEPS + 1) * HS_T_STRIDE * 4;
    float* gi               = (float*)w;          w += (size_t)T_STEPS * BATCH * 3 * HDIM * 4;

    prep_kernel<<<2048, 256, 0, stream>>>(h0, tseq, emb, w_ih, w_hh, w_cls,
                                          wcls_bf, wih_bf, whh_hi, whh_lo,
                                          x_bf, hs32);

    // GI = X @ W_ih^T + b_ih : M=1536, N=3072, K=512  (288 wgs, %8==0)
    gemm_lds<false><<<(T_STEPS * BATCH / 128) * (3 * HDIM / 128), 256, 0, stream>>>(
        x_bf, wih_bf, b_ih, gi, EDIM, 3 * HDIM, T_STEPS * BATCH / 128);

    // all 48 GRU steps: fence-free dataflow persistent kernel
    gru_persist<<<GRU_BLOCKS, 256, 0, stream>>>(hs32, whh_hi, whh_lo, gi, b_hh);

    // scores = Hs[1..48] @ W_cls^T + b_cls : M=1536, N=32000, K=1024 (3000 wgs, %8==0)
    gemm_lds<true><<<(T_STEPS * BATCH / 128) * (VOCAB / 128), 256, 0, stream>>>(
        (const unsigned short*)hs32, wcls_bf, b_cls, out, HDIM, VOCAB, T_STEPS * BATCH / 128);
}

// Round 7
// 1115.007 us; speedup vs baseline: 1.1101x; 1.0446x over previous
//
#include <hip/hip_runtime.h>
#include <hip/hip_bf16.h>

typedef __attribute__((ext_vector_type(8))) short short8;
typedef __attribute__((ext_vector_type(4))) float f32x4;

#define T_STEPS 48
#define BATCH 32
#define EDIM 512
#define HDIM 1024
#define VOCAB 32000
#define GRU_BLOCKS 128
#define JPB 8
#define SENT 0x7FFF7FFFu

// packed h storage: ull words, [t(49)][k_pair(512)][b(32)]
// each ull: low32 = hi-plane (bf16 j=2w | j=2w+1<<16), high32 = lo-plane
#define HS_T_STRIDE 16384          // ulls per t-slot

__device__ __forceinline__ unsigned short f2bf(float f) {
    __hip_bfloat16 h = __float2bfloat16(f);
    return *reinterpret_cast<unsigned short*>(&h);
}
__device__ __forceinline__ float bf2f(unsigned short u) {
    union { unsigned int i; float f; } v;
    v.i = ((unsigned int)u) << 16;
    return v.f;
}

typedef __attribute__((address_space(1))) const void GAS;
typedef __attribute__((address_space(3))) void LAS;
__device__ __forceinline__ void gload_lds16(const unsigned short* g, unsigned short* l) {
    __builtin_amdgcn_global_load_lds((GAS*)g, (LAS*)(unsigned)(uintptr_t)l, 16, 0, 0);
}

// ---------------- prep: conversions, gather, h0 pack (transposed), sentinel fill ----------------
__global__ __launch_bounds__(256) void prep_kernel(
    const float* __restrict__ h0, const int* __restrict__ tseq,
    const float* __restrict__ emb, const float* __restrict__ w_ih,
    const float* __restrict__ w_hh, const float* __restrict__ w_cls,
    unsigned short* __restrict__ wcls_bf, unsigned short* __restrict__ wih_bf,
    unsigned short* __restrict__ whh_hi, unsigned short* __restrict__ whh_lo,
    unsigned short* __restrict__ x_bf, unsigned long long* __restrict__ hs64)
{
    const long R0 = (long)VOCAB * HDIM / 4;           // w_cls
    const long R1 = (long)3 * HDIM * EDIM / 4;        // w_ih
    const long R2 = (long)3 * HDIM * HDIM / 4;        // w_hh hi+lo
    const long R3 = (long)T_STEPS * BATCH * EDIM / 4; // X gather
    const long R4 = (long)HS_T_STRIDE;                // h0 -> packed slot 0
    const long R5 = (long)T_STEPS * HS_T_STRIDE / 2;  // sentinel fill t=1..48 (uint4 = 2 ull)
    const long total = R0 + R1 + R2 + R3 + R4 + R5;

    for (long i = (long)blockIdx.x * blockDim.x + threadIdx.x; i < total;
         i += (long)gridDim.x * blockDim.x) {
        if (i < R0) {
            float4 v = reinterpret_cast<const float4*>(w_cls)[i];
            ushort4 u = { f2bf(v.x), f2bf(v.y), f2bf(v.z), f2bf(v.w) };
            *reinterpret_cast<ushort4*>(wcls_bf + i * 4) = u;
        } else if (i < R0 + R1) {
            long j = i - R0;
            float4 v = reinterpret_cast<const float4*>(w_ih)[j];
            ushort4 u = { f2bf(v.x), f2bf(v.y), f2bf(v.z), f2bf(v.w) };
            *reinterpret_cast<ushort4*>(wih_bf + j * 4) = u;
        } else if (i < R0 + R1 + R2) {
            long j = i - R0 - R1;
            float4 v = reinterpret_cast<const float4*>(w_hh)[j];
            ushort4 hi = { f2bf(v.x), f2bf(v.y), f2bf(v.z), f2bf(v.w) };
            ushort4 lo = { f2bf(v.x - bf2f(hi.x)), f2bf(v.y - bf2f(hi.y)),
                           f2bf(v.z - bf2f(hi.z)), f2bf(v.w - bf2f(hi.w)) };
            *reinterpret_cast<ushort4*>(whh_hi + j * 4) = hi;
            *reinterpret_cast<ushort4*>(whh_lo + j * 4) = lo;
        } else if (i < R0 + R1 + R2 + R3) {
            long j = i - R0 - R1 - R2;
            int m = (int)(j >> 7);
            int kk4 = (int)(j & 127);
            int t = m >> 5, b = m & 31;
            int tok = tseq[b * T_STEPS + t];
            float4 v = reinterpret_cast<const float4*>(emb)[(long)tok * (EDIM / 4) + kk4];
            ushort4 u = { f2bf(v.x), f2bf(v.y), f2bf(v.z), f2bf(v.w) };
            *reinterpret_cast<ushort4*>(x_bf + (long)m * EDIM + kk4 * 4) = u;
        } else if (i < R0 + R1 + R2 + R3 + R4) {
            long j = i - R0 - R1 - R2 - R3;       // ull index: w*32 + b
            int w = (int)(j >> 5), b = (int)(j & 31);
            float f0 = h0[b * HDIM + 2 * w];
            float f1 = h0[b * HDIM + 2 * w + 1];
            unsigned short h0a = f2bf(f0), h1a = f2bf(f1);
            unsigned short l0 = f2bf(f0 - bf2f(h0a)), l1 = f2bf(f1 - bf2f(h1a));
            unsigned hw = (unsigned)h0a | ((unsigned)h1a << 16);
            unsigned lw = (unsigned)l0 | ((unsigned)l1 << 16);
            hs64[j] = (unsigned long long)hw | ((unsigned long long)lw << 32);
        } else {
            long j = i - R0 - R1 - R2 - R3 - R4;
            uint4 s = { SENT, SENT, SENT, SENT };
            reinterpret_cast<uint4*>(hs64 + HS_T_STRIDE)[j] = s;   // t=1..48
        }
    }
}

// ---------------- bf16 MFMA GEMM (gload_lds staging, XCD swizzle) ----------------
template <bool SCORES>
__global__ __launch_bounds__(256) void gemm_lds(
    const unsigned short* __restrict__ A, const unsigned short* __restrict__ B,
    const float* __restrict__ bias, float* __restrict__ C, int K, int Ntot, int nM)
{
    const int nwg = gridDim.x;
    const int lin = blockIdx.x;
    const int q = nwg >> 3;
    const int wg = (lin & 7) * q + (lin >> 3);
    const int mi = wg % nM, ni = wg / nM;
    const int m0 = mi * 128, n0 = ni * 128;

    const int tid = threadIdx.x;
    const int lane = tid & 63;
    const int wid = tid >> 6;
    const int wr = wid >> 1, wc = wid & 1;

    __shared__ __align__(16) unsigned short As[128 * 32];
    __shared__ __align__(16) unsigned short Bs[128 * 32];

    f32x4 acc[4][4] = {};
    const int NT = K >> 5;
    const int srow = (lane >> 2);
    const int skk = (lane & 3) * 8;

    for (int kt = 0; kt < NT; ++kt) {
        __syncthreads();
        {
            const int kb = kt * 32;
#pragma unroll
            for (int h2 = 0; h2 < 2; ++h2) {
                const int i = wid + h2 * 4;
                const int row = i * 16 + srow;
                gload_lds16(A + (size_t)(m0 + row) * K + kb + skk, As + i * 512);
                gload_lds16(B + (size_t)(n0 + row) * K + kb + skk, Bs + i * 512);
            }
        }
        __syncthreads();

        const int kg = lane >> 4;
        const int l15 = lane & 15;
        short8 af[4], bf[4];
#pragma unroll
        for (int i = 0; i < 4; ++i) {
            af[i] = *(const short8*)(As + ((wr * 64 + i * 16 + l15) * 32 + kg * 8));
            bf[i] = *(const short8*)(Bs + ((wc * 64 + i * 16 + l15) * 32 + kg * 8));
        }
#pragma unroll
        for (int i = 0; i < 4; ++i)
#pragma unroll
            for (int j = 0; j < 4; ++j)
                acc[i][j] = __builtin_amdgcn_mfma_f32_16x16x32_bf16(af[i], bf[j], acc[i][j], 0, 0, 0);
    }

    const int l15 = lane & 15, lhi = lane >> 4;
#pragma unroll
    for (int i = 0; i < 4; ++i) {
#pragma unroll
        for (int j = 0; j < 4; ++j) {
            int col = n0 + wc * 64 + j * 16 + l15;
            float bv = bias[col];
#pragma unroll
            for (int q2 = 0; q2 < 4; ++q2) {
                int row = m0 + wr * 64 + i * 16 + lhi * 4 + q2;
                float v = acc[i][j][q2] + bv;
                if (SCORES) {
                    int t = row >> 5, b = row & 31;
                    C[(size_t)(b * T_STEPS + t) * Ntot + col] = v;
                } else {
                    C[(size_t)row * Ntot + col] = v;
                }
            }
        }
    }
}

// ---------------- persistent GRU: fence-free dataflow, COALESCED b64 h-exchange ----------------
// 128 blocks x 256 threads. W_hh in LDS. h exchanged via hs64[t][k_pair][b]:
// consecutive lanes read consecutive 8B -> full MALL-line utilization.
__global__ __launch_bounds__(256, 1) void gru_persist(
    unsigned long long* __restrict__ hs64, unsigned int* __restrict__ hrow32,
    const unsigned short* __restrict__ whh_hi, const unsigned short* __restrict__ whh_lo,
    const float* __restrict__ gi, const float* __restrict__ b_hh)
{
    const int j0 = blockIdx.x * JPB;
    const int tid = threadIdx.x;
    const int lane = tid & 63, wid = tid >> 6;     // 4 waves
    const int l15 = lane & 15, kg = lane >> 4;     // kg 0..3
    const int kq = wid * 256;                      // wave's K-chunk (bf16 units)

    __shared__ __align__(16) unsigned short Wl[2][32][1032];  // 132KB, rows 24..31 zero
    __shared__ float P[4][32][25];

    // one-time W fill (normal cached loads)
    for (int c = tid; c < 32 * 128; c += 256) {
        int row = c >> 7, k8 = (c & 127) * 8;
        short8 vh = {0, 0, 0, 0, 0, 0, 0, 0};
        short8 vl = {0, 0, 0, 0, 0, 0, 0, 0};
        if (row < 24) {
            int g = row >> 3, jj = row & 7;
            size_t off = (size_t)(g * HDIM + j0 + jj) * HDIM + k8;
            vh = *(const short8*)(whh_hi + off);
            vl = *(const short8*)(whh_lo + off);
        }
        *(short8*)&Wl[0][row][k8] = vh;
        *(short8*)&Wl[1][row][k8] = vl;
    }

    // per-thread constants: this thread's (b, jj) gate item
    const int gb = tid >> 3, gjj = tid & 7;
    const int gj = j0 + gjj;
    const float bhr = b_hh[gj];
    const float bhz = b_hh[HDIM + gj];
    const float bhn = b_hh[2 * HDIM + gj];

    // running h for this (b,j), from slot 0
    float hloc;
    {
        unsigned long long v = __hip_atomic_load(hs64 + (size_t)(gj >> 1) * 32 + gb,
                                                 __ATOMIC_RELAXED, __HIP_MEMORY_SCOPE_AGENT);
        unsigned hwd = (unsigned)v, lwd = (unsigned)(v >> 32);
        unsigned short hi = (gj & 1) ? (unsigned short)(hwd >> 16) : (unsigned short)(hwd & 0xffff);
        unsigned short lo = (gj & 1) ? (unsigned short)(lwd >> 16) : (unsigned short)(lwd & 0xffff);
        hloc = bf2f(hi) + bf2f(lo);
    }
    __syncthreads();

    for (int t = 0; t < T_STEPS; ++t) {
        const size_t tb = (size_t)t * HS_T_STRIDE;

        // gi for this step (normal cached loads; overlap with h burst)
        const float* girow = gi + (size_t)(t * BATCH + gb) * (3 * HDIM);
        float xr = girow[gj], xz = girow[HDIM + gj], xn = girow[2 * HDIM + gj];

        // burst-load 64 h-ull (both planes together), coalesced, then sentinel-spin
        unsigned long long wv[8][8];
#pragma unroll
        for (int ks = 0; ks < 8; ++ks) {
            const int wbase = wid * 128 + ks * 16 + kg * 4;   // k-pair index
#pragma unroll
            for (int mi = 0; mi < 2; ++mi) {
                const int b = mi * 16 + l15;
#pragma unroll
                for (int q = 0; q < 4; ++q)
                    wv[ks][mi * 4 + q] = __hip_atomic_load(
                        hs64 + tb + (size_t)(wbase + q) * 32 + b,
                        __ATOMIC_RELAXED, __HIP_MEMORY_SCOPE_AGENT);
            }
        }
#pragma unroll
        for (int ks = 0; ks < 8; ++ks)
#pragma unroll
            for (int i = 0; i < 8; ++i) {
                while (__builtin_expect((unsigned)wv[ks][i] == SENT, 0)) {
                    __builtin_amdgcn_s_sleep(1);
                    const int mi = i >> 2, q = i & 3;
                    wv[ks][i] = __hip_atomic_load(
                        hs64 + tb + (size_t)(wid * 128 + ks * 16 + kg * 4 + q) * 32 + (mi * 16 + l15),
                        __ATOMIC_RELAXED, __HIP_MEMORY_SCOPE_AGENT);
                }
            }

        // MFMA: acc[mi][fr] over 8 K-slices, bf16x3
        f32x4 acc[2][2] = {};
#pragma unroll
        for (int ks = 0; ks < 8; ++ks) {
            const int kb = kq + ks * 32 + kg * 8;
            union U8 { unsigned u[4]; short8 s; };
            short8 ah[2], al[2];
#pragma unroll
            for (int mi = 0; mi < 2; ++mi) {
                U8 x, y;
#pragma unroll
                for (int q = 0; q < 4; ++q) {
                    x.u[q] = (unsigned)wv[ks][mi * 4 + q];
                    y.u[q] = (unsigned)(wv[ks][mi * 4 + q] >> 32);
                }
                ah[mi] = x.s; al[mi] = y.s;
            }
#pragma unroll
            for (int fr = 0; fr < 2; ++fr) {
                short8 bhi = *(const short8*)&Wl[0][fr * 16 + l15][kb];
                short8 blo = *(const short8*)&Wl[1][fr * 16 + l15][kb];
#pragma unroll
                for (int mi = 0; mi < 2; ++mi) {
                    acc[mi][fr] = __builtin_amdgcn_mfma_f32_16x16x32_bf16(ah[mi], bhi, acc[mi][fr], 0, 0, 0);
                    acc[mi][fr] = __builtin_amdgcn_mfma_f32_16x16x32_bf16(ah[mi], blo, acc[mi][fr], 0, 0, 0);
                    acc[mi][fr] = __builtin_amdgcn_mfma_f32_16x16x32_bf16(al[mi], bhi, acc[mi][fr], 0, 0, 0);
                }
            }
        }

        // scatter partials: C/D map col(l15)=W-row, row(kg*4+q)=batch
#pragma unroll
        for (int mi = 0; mi < 2; ++mi)
#pragma unroll
            for (int fr = 0; fr < 2; ++fr)
                if (fr == 0 || l15 < 8)
#pragma unroll
                    for (int q = 0; q < 4; ++q)
                        P[wid][mi * 16 + kg * 4 + q][fr * 16 + l15] = acc[mi][fr][q];
        __syncthreads();

        // gates + immediate publish (shfl pack, no LDS round-trip)
        {
            float ghr = 0.f, ghz = 0.f, ghn = 0.f;
#pragma unroll
            for (int w = 0; w < 4; ++w) {
                ghr += P[w][gb][gjj];
                ghz += P[w][gb][8 + gjj];
                ghn += P[w][gb][16 + gjj];
            }
            float r = 1.f / (1.f + __expf(-(xr + ghr + bhr)));
            float z = 1.f / (1.f + __expf(-(xz + ghz + bhz)));
            float n = tanhf(xn + r * (ghn + bhn));
            float hnew = (1.f - z) * n + z * hloc;
            hloc = hnew;
            unsigned hv = f2bf(hnew);
            unsigned lv = f2bf(hnew - bf2f((unsigned short)hv));
            unsigned hnb = (unsigned)__shfl_xor((int)hv, 1);
            unsigned lnb = (unsigned)__shfl_xor((int)lv, 1);
            if (!(gjj & 1)) {
                unsigned hw = hv | (hnb << 16);
                unsigned lw = lv | (lnb << 16);
                const int wdx = gj >> 1;
                __hip_atomic_store(hs64 + (size_t)(t + 1) * HS_T_STRIDE + (size_t)wdx * 32 + gb,
                                   (unsigned long long)hw | ((unsigned long long)lw << 32),
                                   __ATOMIC_RELAXED, __HIP_MEMORY_SCOPE_AGENT);
                // row-major bf16-hi copy for the scores GEMM (normal store; kernel-boundary flush)
                hrow32[((size_t)t * BATCH + gb) * 512 + wdx] = hw;
            }
        }
        __syncthreads();   // protect P reuse next iteration
    }
}

extern "C" void kernel_launch(void* const* d_in, const int* in_sizes, int n_in,
                              void* d_out, int out_size, void* d_ws, size_t ws_size,
                              hipStream_t stream) {
    const float* h0    = (const float*)d_in[0];
    const int*   tseq  = (const int*)d_in[1];
    const float* emb   = (const float*)d_in[2];
    const float* w_ih  = (const float*)d_in[3];
    const float* w_hh  = (const float*)d_in[4];
    const float* b_ih  = (const float*)d_in[5];
    const float* b_hh  = (const float*)d_in[6];
    const float* w_cls = (const float*)d_in[7];
    const float* b_cls = (const float*)d_in[8];
    float* out = (float*)d_out;

    char* w = (char*)d_ws;
    unsigned short* wcls_bf = (unsigned short*)w; w += (size_t)VOCAB * HDIM * 2;
    unsigned short* wih_bf  = (unsigned short*)w; w += (size_t)3 * HDIM * EDIM * 2;
    unsigned short* whh_hi  = (unsigned short*)w; w += (size_t)3 * HDIM * HDIM * 2;
    unsigned short* whh_lo  = (unsigned short*)w; w += (size_t)3 * HDIM * HDIM * 2;
    unsigned short* x_bf    = (unsigned short*)w; w += (size_t)T_STEPS * BATCH * EDIM * 2;
    unsigned long long* hs64 = (unsigned long long*)w; w += (size_t)(T_STEPS + 1) * HS_T_STRIDE * 8;
    unsigned int* hrow32    = (unsigned int*)w;   w += (size_t)T_STEPS * BATCH * 512 * 4;
    float* gi               = (float*)w;          w += (size_t)T_STEPS * BATCH * 3 * HDIM * 4;

    prep_kernel<<<2048, 256, 0, stream>>>(h0, tseq, emb, w_ih, w_hh, w_cls,
                                          wcls_bf, wih_bf, whh_hi, whh_lo,
                                          x_bf, hs64);

    // GI = X @ W_ih^T + b_ih : M=1536, N=3072, K=512  (288 wgs, %8==0)
    gemm_lds<false><<<(T_STEPS * BATCH / 128) * (3 * HDIM / 128), 256, 0, stream>>>(
        x_bf, wih_bf, b_ih, gi, EDIM, 3 * HDIM, T_STEPS * BATCH / 128);

    // all 48 GRU steps: fence-free dataflow, coalesced b64 h-exchange
    gru_persist<<<GRU_BLOCKS, 256, 0, stream>>>(hs64, hrow32, whh_hi, whh_lo, gi, b_hh);

    // scores = Hrow @ W_cls^T + b_cls : M=1536, N=32000, K=1024 (3000 wgs, %8==0)
    gemm_lds<true><<<(T_STEPS * BATCH / 128) * (VOCAB / 128), 256, 0, stream>>>(
        (const unsigned short*)hrow32, wcls_bf, b_cls, out, HDIM, VOCAB, T_STEPS * BATCH / 128);
}

// Round 9
// 575.885 us; speedup vs baseline: 2.1492x; 1.9362x over previous
//
#include <hip/hip_runtime.h>
#include <hip/hip_bf16.h>

typedef __attribute__((ext_vector_type(8))) short short8;
typedef __attribute__((ext_vector_type(4))) float f32x4;

#define T_STEPS 48
#define BATCH 32
#define EDIM 512
#define HDIM 1024
#define VOCAB 32000
#define GRU_BLOCKS 128
#define JPB 8
#define SENT 0x7FFF7FFFu

// packed h storage: ull words, [t(49)][k_pair(512)][b(32)]
// each ull: low32 = hi-plane (bf16 j=2w | j=2w+1<<16), high32 = lo-plane
#define HS_T_STRIDE 16384          // ulls per t-slot

__device__ __forceinline__ unsigned short f2bf(float f) {
    __hip_bfloat16 h = __float2bfloat16(f);
    return *reinterpret_cast<unsigned short*>(&h);
}
__device__ __forceinline__ float bf2f(unsigned short u) {
    union { unsigned int i; float f; } v;
    v.i = ((unsigned int)u) << 16;
    return v.f;
}

typedef __attribute__((address_space(1))) const void GAS;
typedef __attribute__((address_space(3))) void LAS;
__device__ __forceinline__ void gload_lds16(const unsigned short* g, unsigned short* l) {
    __builtin_amdgcn_global_load_lds((GAS*)g, (LAS*)(unsigned)(uintptr_t)l, 16, 0, 0);
}

// ---------------- prep: conversions, gather, h0 pack (transposed), sentinel fill ----------------
__global__ __launch_bounds__(256) void prep_kernel(
    const float* __restrict__ h0, const int* __restrict__ tseq,
    const float* __restrict__ emb, const float* __restrict__ w_ih,
    const float* __restrict__ w_hh, const float* __restrict__ w_cls,
    unsigned short* __restrict__ wcls_bf, unsigned short* __restrict__ wih_bf,
    unsigned short* __restrict__ whh_hi, unsigned short* __restrict__ whh_lo,
    unsigned short* __restrict__ x_bf, unsigned long long* __restrict__ hs64)
{
    const long R0 = (long)VOCAB * HDIM / 4;           // w_cls
    const long R1 = (long)3 * HDIM * EDIM / 4;        // w_ih
    const long R2 = (long)3 * HDIM * HDIM / 4;        // w_hh hi+lo
    const long R3 = (long)T_STEPS * BATCH * EDIM / 4; // X gather
    const long R4 = (long)HS_T_STRIDE;                // h0 -> packed slot 0
    const long R5 = (long)T_STEPS * HS_T_STRIDE / 2;  // sentinel fill t=1..48 (uint4 = 2 ull)
    const long total = R0 + R1 + R2 + R3 + R4 + R5;

    for (long i = (long)blockIdx.x * blockDim.x + threadIdx.x; i < total;
         i += (long)gridDim.x * blockDim.x) {
        if (i < R0) {
            float4 v = reinterpret_cast<const float4*>(w_cls)[i];
            ushort4 u = { f2bf(v.x), f2bf(v.y), f2bf(v.z), f2bf(v.w) };
            *reinterpret_cast<ushort4*>(wcls_bf + i * 4) = u;
        } else if (i < R0 + R1) {
            long j = i - R0;
            float4 v = reinterpret_cast<const float4*>(w_ih)[j];
            ushort4 u = { f2bf(v.x), f2bf(v.y), f2bf(v.z), f2bf(v.w) };
            *reinterpret_cast<ushort4*>(wih_bf + j * 4) = u;
        } else if (i < R0 + R1 + R2) {
            long j = i - R0 - R1;
            float4 v = reinterpret_cast<const float4*>(w_hh)[j];
            ushort4 hi = { f2bf(v.x), f2bf(v.y), f2bf(v.z), f2bf(v.w) };
            ushort4 lo = { f2bf(v.x - bf2f(hi.x)), f2bf(v.y - bf2f(hi.y)),
                           f2bf(v.z - bf2f(hi.z)), f2bf(v.w - bf2f(hi.w)) };
            *reinterpret_cast<ushort4*>(whh_hi + j * 4) = hi;
            *reinterpret_cast<ushort4*>(whh_lo + j * 4) = lo;
        } else if (i < R0 + R1 + R2 + R3) {
            long j = i - R0 - R1 - R2;
            int m = (int)(j >> 7);
            int kk4 = (int)(j & 127);
            int t = m >> 5, b = m & 31;
            int tok = tseq[b * T_STEPS + t];
            float4 v = reinterpret_cast<const float4*>(emb)[(long)tok * (EDIM / 4) + kk4];
            ushort4 u = { f2bf(v.x), f2bf(v.y), f2bf(v.z), f2bf(v.w) };
            *reinterpret_cast<ushort4*>(x_bf + (long)m * EDIM + kk4 * 4) = u;
        } else if (i < R0 + R1 + R2 + R3 + R4) {
            long j = i - R0 - R1 - R2 - R3;       // ull index: w*32 + b
            int w = (int)(j >> 5), b = (int)(j & 31);
            float f0 = h0[b * HDIM + 2 * w];
            float f1 = h0[b * HDIM + 2 * w + 1];
            unsigned short h0a = f2bf(f0), h1a = f2bf(f1);
            unsigned short l0 = f2bf(f0 - bf2f(h0a)), l1 = f2bf(f1 - bf2f(h1a));
            unsigned hw = (unsigned)h0a | ((unsigned)h1a << 16);
            unsigned lw = (unsigned)l0 | ((unsigned)l1 << 16);
            hs64[j] = (unsigned long long)hw | ((unsigned long long)lw << 32);
        } else {
            long j = i - R0 - R1 - R2 - R3 - R4;
            uint4 s = { SENT, SENT, SENT, SENT };
            reinterpret_cast<uint4*>(hs64 + HS_T_STRIDE)[j] = s;   // t=1..48
        }
    }
}

// ---------------- bf16 MFMA GEMM (gload_lds staging, XCD swizzle) ----------------
template <bool SCORES>
__global__ __launch_bounds__(256) void gemm_lds(
    const unsigned short* __restrict__ A, const unsigned short* __restrict__ B,
    const float* __restrict__ bias, float* __restrict__ C, int K, int Ntot, int nM)
{
    const int nwg = gridDim.x;
    const int lin = blockIdx.x;
    const int q = nwg >> 3;
    const int wg = (lin & 7) * q + (lin >> 3);
    const int mi = wg % nM, ni = wg / nM;
    const int m0 = mi * 128, n0 = ni * 128;

    const int tid = threadIdx.x;
    const int lane = tid & 63;
    const int wid = tid >> 6;
    const int wr = wid >> 1, wc = wid & 1;

    __shared__ __align__(16) unsigned short As[128 * 32];
    __shared__ __align__(16) unsigned short Bs[128 * 32];

    f32x4 acc[4][4] = {};
    const int NT = K >> 5;
    const int srow = (lane >> 2);
    const int skk = (lane & 3) * 8;

    for (int kt = 0; kt < NT; ++kt) {
        __syncthreads();
        {
            const int kb = kt * 32;
#pragma unroll
            for (int h2 = 0; h2 < 2; ++h2) {
                const int i = wid + h2 * 4;
                const int row = i * 16 + srow;
                gload_lds16(A + (size_t)(m0 + row) * K + kb + skk, As + i * 512);
                gload_lds16(B + (size_t)(n0 + row) * K + kb + skk, Bs + i * 512);
            }
        }
        __syncthreads();

        const int kg = lane >> 4;
        const int l15 = lane & 15;
        short8 af[4], bf[4];
#pragma unroll
        for (int i = 0; i < 4; ++i) {
            af[i] = *(const short8*)(As + ((wr * 64 + i * 16 + l15) * 32 + kg * 8));
            bf[i] = *(const short8*)(Bs + ((wc * 64 + i * 16 + l15) * 32 + kg * 8));
        }
#pragma unroll
        for (int i = 0; i < 4; ++i)
#pragma unroll
            for (int j = 0; j < 4; ++j)
                acc[i][j] = __builtin_amdgcn_mfma_f32_16x16x32_bf16(af[i], bf[j], acc[i][j], 0, 0, 0);
    }

    const int l15 = lane & 15, lhi = lane >> 4;
#pragma unroll
    for (int i = 0; i < 4; ++i) {
#pragma unroll
        for (int j = 0; j < 4; ++j) {
            int col = n0 + wc * 64 + j * 16 + l15;
            float bv = bias[col];
#pragma unroll
            for (int q2 = 0; q2 < 4; ++q2) {
                int row = m0 + wr * 64 + i * 16 + lhi * 4 + q2;
                float v = acc[i][j][q2] + bv;
                if (SCORES) {
                    int t = row >> 5, b = row & 31;
                    C[(size_t)(b * T_STEPS + t) * Ntot + col] = v;
                } else {
                    C[(size_t)row * Ntot + col] = v;
                }
            }
        }
    }
}

// ---------------- persistent GRU: sentinel dataflow with PARALLEL retry rounds ----------------
// 128 blocks x 256 threads. W_hh in LDS. h exchanged via hs64[t][k_pair][b]
// (coalesced b64). Data-as-signal: initial burst, then each retry round reloads
// ALL still-sentinel words in parallel (~1 MALL latency/round, not per word).
__global__ __launch_bounds__(256, 1) void gru_persist(
    unsigned long long* __restrict__ hs64, unsigned int* __restrict__ hrow32,
    const unsigned short* __restrict__ whh_hi, const unsigned short* __restrict__ whh_lo,
    const float* __restrict__ gi, const float* __restrict__ b_hh)
{
    const int j0 = blockIdx.x * JPB;
    const int tid = threadIdx.x;
    const int lane = tid & 63, wid = tid >> 6;     // 4 waves
    const int l15 = lane & 15, kg = lane >> 4;     // kg 0..3
    const int kq = wid * 256;                      // wave's K-chunk (bf16 units)

    __shared__ __align__(16) unsigned short Wl[2][32][1032];  // 132KB, rows 24..31 zero
    __shared__ float P[4][32][25];

    // one-time W fill (normal cached loads)
    for (int c = tid; c < 32 * 128; c += 256) {
        int row = c >> 7, k8 = (c & 127) * 8;
        short8 vh = {0, 0, 0, 0, 0, 0, 0, 0};
        short8 vl = {0, 0, 0, 0, 0, 0, 0, 0};
        if (row < 24) {
            int g = row >> 3, jj = row & 7;
            size_t off = (size_t)(g * HDIM + j0 + jj) * HDIM + k8;
            vh = *(const short8*)(whh_hi + off);
            vl = *(const short8*)(whh_lo + off);
        }
        *(short8*)&Wl[0][row][k8] = vh;
        *(short8*)&Wl[1][row][k8] = vl;
    }

    // per-thread constants: this thread's (b, jj) gate item
    const int gb = tid >> 3, gjj = tid & 7;
    const int gj = j0 + gjj;
    const float bhr = b_hh[gj];
    const float bhz = b_hh[HDIM + gj];
    const float bhn = b_hh[2 * HDIM + gj];

    // running h for this (b,j), from slot 0
    float hloc;
    {
        unsigned long long v = __hip_atomic_load(hs64 + (size_t)(gj >> 1) * 32 + gb,
                                                 __ATOMIC_RELAXED, __HIP_MEMORY_SCOPE_AGENT);
        unsigned hwd = (unsigned)v, lwd = (unsigned)(v >> 32);
        unsigned short hi = (gj & 1) ? (unsigned short)(hwd >> 16) : (unsigned short)(hwd & 0xffff);
        unsigned short lo = (gj & 1) ? (unsigned short)(lwd >> 16) : (unsigned short)(lwd & 0xffff);
        hloc = bf2f(hi) + bf2f(lo);
    }
    __syncthreads();

    for (int t = 0; t < T_STEPS; ++t) {
        const size_t tb = (size_t)t * HS_T_STRIDE;

        // gi for this step (normal cached loads; overlaps the h burst)
        const float* girow = gi + (size_t)(t * BATCH + gb) * (3 * HDIM);
        float xr = girow[gj], xz = girow[HDIM + gj], xn = girow[2 * HDIM + gj];

        // ---- initial burst: 64 independent coalesced b64 loads ----
        unsigned long long wv[8][8];
#pragma unroll
        for (int ks = 0; ks < 8; ++ks) {
            const int wbase = wid * 128 + ks * 16 + kg * 4;   // k-pair index
#pragma unroll
            for (int mi = 0; mi < 2; ++mi) {
                const int b = mi * 16 + l15;
#pragma unroll
                for (int q = 0; q < 4; ++q)
                    wv[ks][mi * 4 + q] = __hip_atomic_load(
                        hs64 + tb + (size_t)(wbase + q) * 32 + b,
                        __ATOMIC_RELAXED, __HIP_MEMORY_SCOPE_AGENT);
            }
        }
        // ---- parallel retry rounds: reload ALL still-sentinel words each round ----
        for (;;) {
            int bad = 0;
#pragma unroll
            for (int ks = 0; ks < 8; ++ks)
#pragma unroll
                for (int i = 0; i < 8; ++i)
                    bad |= ((unsigned)wv[ks][i] == SENT);
            if (!__any(bad)) break;
            __builtin_amdgcn_s_sleep(1);
#pragma unroll
            for (int ks = 0; ks < 8; ++ks)
#pragma unroll
                for (int i = 0; i < 8; ++i)
                    if ((unsigned)wv[ks][i] == SENT) {
                        const int mi = i >> 2, q = i & 3;
                        wv[ks][i] = __hip_atomic_load(
                            hs64 + tb + (size_t)(wid * 128 + ks * 16 + kg * 4 + q) * 32 + (mi * 16 + l15),
                            __ATOMIC_RELAXED, __HIP_MEMORY_SCOPE_AGENT);
                    }
        }

        // MFMA: acc[mi][fr] over 8 K-slices, bf16x3
        f32x4 acc[2][2] = {};
#pragma unroll
        for (int ks = 0; ks < 8; ++ks) {
            const int kb = kq + ks * 32 + kg * 8;
            union U8 { unsigned u[4]; short8 s; };
            short8 ah[2], al[2];
#pragma unroll
            for (int mi = 0; mi < 2; ++mi) {
                U8 x, y;
#pragma unroll
                for (int q = 0; q < 4; ++q) {
                    x.u[q] = (unsigned)wv[ks][mi * 4 + q];
                    y.u[q] = (unsigned)(wv[ks][mi * 4 + q] >> 32);
                }
                ah[mi] = x.s; al[mi] = y.s;
            }
#pragma unroll
            for (int fr = 0; fr < 2; ++fr) {
                short8 bhi = *(const short8*)&Wl[0][fr * 16 + l15][kb];
                short8 blo = *(const short8*)&Wl[1][fr * 16 + l15][kb];
#pragma unroll
                for (int mi = 0; mi < 2; ++mi) {
                    acc[mi][fr] = __builtin_amdgcn_mfma_f32_16x16x32_bf16(ah[mi], bhi, acc[mi][fr], 0, 0, 0);
                    acc[mi][fr] = __builtin_amdgcn_mfma_f32_16x16x32_bf16(ah[mi], blo, acc[mi][fr], 0, 0, 0);
                    acc[mi][fr] = __builtin_amdgcn_mfma_f32_16x16x32_bf16(al[mi], bhi, acc[mi][fr], 0, 0, 0);
                }
            }
        }

        // scatter partials: C/D map col(l15)=W-row, row(kg*4+q)=batch
#pragma unroll
        for (int mi = 0; mi < 2; ++mi)
#pragma unroll
            for (int fr = 0; fr < 2; ++fr)
                if (fr == 0 || l15 < 8)
#pragma unroll
                    for (int q = 0; q < 4; ++q)
                        P[wid][mi * 16 + kg * 4 + q][fr * 16 + l15] = acc[mi][fr][q];
        __syncthreads();

        // gates + immediate publish (shfl pack, no LDS round-trip)
        {
            float ghr = 0.f, ghz = 0.f, ghn = 0.f;
#pragma unroll
            for (int w = 0; w < 4; ++w) {
                ghr += P[w][gb][gjj];
                ghz += P[w][gb][8 + gjj];
                ghn += P[w][gb][16 + gjj];
            }
            float r = 1.f / (1.f + __expf(-(xr + ghr + bhr)));
            float z = 1.f / (1.f + __expf(-(xz + ghz + bhz)));
            float n = tanhf(xn + r * (ghn + bhn));
            float hnew = (1.f - z) * n + z * hloc;
            hloc = hnew;
            unsigned hv = f2bf(hnew);
            unsigned lv = f2bf(hnew - bf2f((unsigned short)hv));
            unsigned hnb = (unsigned)__shfl_xor((int)hv, 1);
            unsigned lnb = (unsigned)__shfl_xor((int)lv, 1);
            if (!(gjj & 1)) {
                unsigned hw = hv | (hnb << 16);
                unsigned lw = lv | (lnb << 16);
                const int wdx = gj >> 1;
                __hip_atomic_store(hs64 + (size_t)(t + 1) * HS_T_STRIDE + (size_t)wdx * 32 + gb,
                                   (unsigned long long)hw | ((unsigned long long)lw << 32),
                                   __ATOMIC_RELAXED, __HIP_MEMORY_SCOPE_AGENT);
                // row-major bf16-hi copy for the scores GEMM (kernel-boundary flush)
                hrow32[((size_t)t * BATCH + gb) * 512 + wdx] = hw;
            }
        }
        __syncthreads();   // protect P reuse next iteration
    }
}

extern "C" void kernel_launch(void* const* d_in, const int* in_sizes, int n_in,
                              void* d_out, int out_size, void* d_ws, size_t ws_size,
                              hipStream_t stream) {
    const float* h0    = (const float*)d_in[0];
    const int*   tseq  = (const int*)d_in[1];
    const float* emb   = (const float*)d_in[2];
    const float* w_ih  = (const float*)d_in[3];
    const float* w_hh  = (const float*)d_in[4];
    const float* b_ih  = (const float*)d_in[5];
    const float* b_hh  = (const float*)d_in[6];
    const float* w_cls = (const float*)d_in[7];
    const float* b_cls = (const float*)d_in[8];
    float* out = (float*)d_out;

    char* w = (char*)d_ws;
    unsigned short* wcls_bf = (unsigned short*)w; w += (size_t)VOCAB * HDIM * 2;
    unsigned short* wih_bf  = (unsigned short*)w; w += (size_t)3 * HDIM * EDIM * 2;
    unsigned short* whh_hi  = (unsigned short*)w; w += (size_t)3 * HDIM * HDIM * 2;
    unsigned short* whh_lo  = (unsigned short*)w; w += (size_t)3 * HDIM * HDIM * 2;
    unsigned short* x_bf    = (unsigned short*)w; w += (size_t)T_STEPS * BATCH * EDIM * 2;
    unsigned long long* hs64 = (unsigned long long*)w; w += (size_t)(T_STEPS + 1) * HS_T_STRIDE * 8;
    unsigned int* hrow32    = (unsigned int*)w;   w += (size_t)T_STEPS * BATCH * 512 * 4;
    float* gi               = (float*)w;          w += (size_t)T_STEPS * BATCH * 3 * HDIM * 4;

    prep_kernel<<<2048, 256, 0, stream>>>(h0, tseq, emb, w_ih, w_hh, w_cls,
                                          wcls_bf, wih_bf, whh_hi, whh_lo,
                                          x_bf, hs64);

    // GI = X @ W_ih^T + b_ih : M=1536, N=3072, K=512  (288 wgs, %8==0)
    gemm_lds<false><<<(T_STEPS * BATCH / 128) * (3 * HDIM / 128), 256, 0, stream>>>(
        x_bf, wih_bf, b_ih, gi, EDIM, 3 * HDIM, T_STEPS * BATCH / 128);

    // all 48 GRU steps: sentinel dataflow with parallel retry rounds
    gru_persist<<<GRU_BLOCKS, 256, 0, stream>>>(hs64, hrow32, whh_hi, whh_lo, gi, b_hh);

    // scores = Hrow @ W_cls^T + b_cls : M=1536, N=32000, K=1024 (3000 wgs, %8==0)
    gemm_lds<true><<<(T_STEPS * BATCH / 128) * (VOCAB / 128), 256, 0, stream>>>(
        (const unsigned short*)hrow32, wcls_bf, b_cls, out, HDIM, VOCAB, T_STEPS * BATCH / 128);
}

// Round 10
// 536.380 us; speedup vs baseline: 2.3075x; 1.0737x over previous
//
#include <hip/hip_runtime.h>
#include <hip/hip_bf16.h>

typedef __attribute__((ext_vector_type(8))) short short8;
typedef __attribute__((ext_vector_type(4))) float f32x4;

#define T_STEPS 48
#define BATCH 32
#define EDIM 512
#define HDIM 1024
#define VOCAB 32000
#define GRU_BLOCKS 128
#define JPB 8
#define SENT 0x7FFF7FFFu

// packed h storage: ull words, [t(49)][k_pair(512)][b(32)]
// each ull: low32 = hi-plane (bf16 j=2w | j=2w+1<<16), high32 = lo-plane
#define HS_T_STRIDE 16384          // ulls per t-slot

__device__ __forceinline__ unsigned short f2bf(float f) {
    __hip_bfloat16 h = __float2bfloat16(f);
    return *reinterpret_cast<unsigned short*>(&h);
}
__device__ __forceinline__ float bf2f(unsigned short u) {
    union { unsigned int i; float f; } v;
    v.i = ((unsigned int)u) << 16;
    return v.f;
}

typedef __attribute__((address_space(1))) const void GAS;
typedef __attribute__((address_space(3))) void LAS;
__device__ __forceinline__ void gload_lds16(const unsigned short* g, unsigned short* l) {
    __builtin_amdgcn_global_load_lds((GAS*)g, (LAS*)(unsigned)(uintptr_t)l, 16, 0, 0);
}

// ---------------- prep: conversions, gather, h0 pack, sentinel fill, cnt zero ----------------
__global__ __launch_bounds__(256) void prep_kernel(
    const float* __restrict__ h0, const int* __restrict__ tseq,
    const float* __restrict__ emb, const float* __restrict__ w_ih,
    const float* __restrict__ w_hh, const float* __restrict__ w_cls,
    unsigned short* __restrict__ wcls_bf, unsigned short* __restrict__ wih_bf,
    unsigned short* __restrict__ whh_hi, unsigned short* __restrict__ whh_lo,
    unsigned short* __restrict__ x_bf, unsigned long long* __restrict__ hs64,
    unsigned int* __restrict__ cnt)
{
    const long R0 = (long)VOCAB * HDIM / 4;           // w_cls
    const long R1 = (long)3 * HDIM * EDIM / 4;        // w_ih
    const long R2 = (long)3 * HDIM * HDIM / 4;        // w_hh hi+lo
    const long R3 = (long)T_STEPS * BATCH * EDIM / 4; // X gather
    const long R4 = (long)HS_T_STRIDE;                // h0 -> packed slot 0
    const long R5 = (long)T_STEPS * HS_T_STRIDE / 2;  // sentinel fill t=1..48 (uint4 = 2 ull)
    const long R6 = 16;                               // cnt zero (16 x uint4 = 64 uints)
    const long total = R0 + R1 + R2 + R3 + R4 + R5 + R6;

    for (long i = (long)blockIdx.x * blockDim.x + threadIdx.x; i < total;
         i += (long)gridDim.x * blockDim.x) {
        if (i < R0) {
            float4 v = reinterpret_cast<const float4*>(w_cls)[i];
            ushort4 u = { f2bf(v.x), f2bf(v.y), f2bf(v.z), f2bf(v.w) };
            *reinterpret_cast<ushort4*>(wcls_bf + i * 4) = u;
        } else if (i < R0 + R1) {
            long j = i - R0;
            float4 v = reinterpret_cast<const float4*>(w_ih)[j];
            ushort4 u = { f2bf(v.x), f2bf(v.y), f2bf(v.z), f2bf(v.w) };
            *reinterpret_cast<ushort4*>(wih_bf + j * 4) = u;
        } else if (i < R0 + R1 + R2) {
            long j = i - R0 - R1;
            float4 v = reinterpret_cast<const float4*>(w_hh)[j];
            ushort4 hi = { f2bf(v.x), f2bf(v.y), f2bf(v.z), f2bf(v.w) };
            ushort4 lo = { f2bf(v.x - bf2f(hi.x)), f2bf(v.y - bf2f(hi.y)),
                           f2bf(v.z - bf2f(hi.z)), f2bf(v.w - bf2f(hi.w)) };
            *reinterpret_cast<ushort4*>(whh_hi + j * 4) = hi;
            *reinterpret_cast<ushort4*>(whh_lo + j * 4) = lo;
        } else if (i < R0 + R1 + R2 + R3) {
            long j = i - R0 - R1 - R2;
            int m = (int)(j >> 7);
            int kk4 = (int)(j & 127);
            int t = m >> 5, b = m & 31;
            int tok = tseq[b * T_STEPS + t];
            float4 v = reinterpret_cast<const float4*>(emb)[(long)tok * (EDIM / 4) + kk4];
            ushort4 u = { f2bf(v.x), f2bf(v.y), f2bf(v.z), f2bf(v.w) };
            *reinterpret_cast<ushort4*>(x_bf + (long)m * EDIM + kk4 * 4) = u;
        } else if (i < R0 + R1 + R2 + R3 + R4) {
            long j = i - R0 - R1 - R2 - R3;       // ull index: w*32 + b
            int w = (int)(j >> 5), b = (int)(j & 31);
            float f0 = h0[b * HDIM + 2 * w];
            float f1 = h0[b * HDIM + 2 * w + 1];
            unsigned short h0a = f2bf(f0), h1a = f2bf(f1);
            unsigned short l0 = f2bf(f0 - bf2f(h0a)), l1 = f2bf(f1 - bf2f(h1a));
            unsigned hw = (unsigned)h0a | ((unsigned)h1a << 16);
            unsigned lw = (unsigned)l0 | ((unsigned)l1 << 16);
            hs64[j] = (unsigned long long)hw | ((unsigned long long)lw << 32);
        } else if (i < R0 + R1 + R2 + R3 + R4 + R5) {
            long j = i - R0 - R1 - R2 - R3 - R4;
            uint4 s = { SENT, SENT, SENT, SENT };
            reinterpret_cast<uint4*>(hs64 + HS_T_STRIDE)[j] = s;   // t=1..48
        } else {
            long j = i - R0 - R1 - R2 - R3 - R4 - R5;
            uint4 z = { 0u, 0u, 0u, 0u };
            reinterpret_cast<uint4*>(cnt)[j] = z;
        }
    }
}

// ---------------- bf16 MFMA GEMM (gload_lds staging, XCD swizzle) ----------------
template <bool SCORES>
__global__ __launch_bounds__(256) void gemm_lds(
    const unsigned short* __restrict__ A, const unsigned short* __restrict__ B,
    const float* __restrict__ bias, float* __restrict__ C, int K, int Ntot, int nM)
{
    const int nwg = gridDim.x;
    const int lin = blockIdx.x;
    const int q = nwg >> 3;
    const int wg = (lin & 7) * q + (lin >> 3);
    const int mi = wg % nM, ni = wg / nM;
    const int m0 = mi * 128, n0 = ni * 128;

    const int tid = threadIdx.x;
    const int lane = tid & 63;
    const int wid = tid >> 6;
    const int wr = wid >> 1, wc = wid & 1;

    __shared__ __align__(16) unsigned short As[128 * 32];
    __shared__ __align__(16) unsigned short Bs[128 * 32];

    f32x4 acc[4][4] = {};
    const int NT = K >> 5;
    const int srow = (lane >> 2);
    const int skk = (lane & 3) * 8;

    for (int kt = 0; kt < NT; ++kt) {
        __syncthreads();
        {
            const int kb = kt * 32;
#pragma unroll
            for (int h2 = 0; h2 < 2; ++h2) {
                const int i = wid + h2 * 4;
                const int row = i * 16 + srow;
                gload_lds16(A + (size_t)(m0 + row) * K + kb + skk, As + i * 512);
                gload_lds16(B + (size_t)(n0 + row) * K + kb + skk, Bs + i * 512);
            }
        }
        __syncthreads();

        const int kg = lane >> 4;
        const int l15 = lane & 15;
        short8 af[4], bf[4];
#pragma unroll
        for (int i = 0; i < 4; ++i) {
            af[i] = *(const short8*)(As + ((wr * 64 + i * 16 + l15) * 32 + kg * 8));
            bf[i] = *(const short8*)(Bs + ((wc * 64 + i * 16 + l15) * 32 + kg * 8));
        }
#pragma unroll
        for (int i = 0; i < 4; ++i)
#pragma unroll
            for (int j = 0; j < 4; ++j)
                acc[i][j] = __builtin_amdgcn_mfma_f32_16x16x32_bf16(af[i], bf[j], acc[i][j], 0, 0, 0);
    }

    const int l15 = lane & 15, lhi = lane >> 4;
#pragma unroll
    for (int i = 0; i < 4; ++i) {
#pragma unroll
        for (int j = 0; j < 4; ++j) {
            int col = n0 + wc * 64 + j * 16 + l15;
            float bv = bias[col];
#pragma unroll
            for (int q2 = 0; q2 < 4; ++q2) {
                int row = m0 + wr * 64 + i * 16 + lhi * 4 + q2;
                float v = acc[i][j][q2] + bv;
                if (SCORES) {
                    int t = row >> 5, b = row & 31;
                    C[(size_t)(b * T_STEPS + t) * Ntot + col] = v;
                } else {
                    C[(size_t)row * Ntot + col] = v;
                }
            }
        }
    }
}

// ---------------- persistent GRU: counter-hinted burst + sentinel backstop ----------------
// 128 blocks x 256 threads. W_hh in LDS. Producer: publish h (atomic b64 stores)
// -> __syncthreads (vmcnt(0) drains -> stores acked at MALL) -> fetch_add(cnt[t+1]).
// Consumer: wave0 polls cnt[t]==128 (one coalesced request/round), barrier, then ONE
// plain-b64 burst; sentinel retry with cache-bypassing atomic loads as backstop.
__global__ __launch_bounds__(256, 1) void gru_persist(
    unsigned long long* __restrict__ hs64, unsigned int* __restrict__ hrow32,
    const unsigned short* __restrict__ whh_hi, const unsigned short* __restrict__ whh_lo,
    const float* __restrict__ gi, const float* __restrict__ b_hh,
    unsigned int* __restrict__ cnt)
{
    const int j0 = blockIdx.x * JPB;
    const int tid = threadIdx.x;
    const int lane = tid & 63, wid = tid >> 6;     // 4 waves
    const int l15 = lane & 15, kg = lane >> 4;     // kg 0..3
    const int kq = wid * 256;                      // wave's K-chunk (bf16 units)

    __shared__ __align__(16) unsigned short Wl[2][32][1032];  // 132KB, rows 24..31 zero
    __shared__ float P[4][32][25];

    // one-time W fill (normal cached loads)
    for (int c = tid; c < 32 * 128; c += 256) {
        int row = c >> 7, k8 = (c & 127) * 8;
        short8 vh = {0, 0, 0, 0, 0, 0, 0, 0};
        short8 vl = {0, 0, 0, 0, 0, 0, 0, 0};
        if (row < 24) {
            int g = row >> 3, jj = row & 7;
            size_t off = (size_t)(g * HDIM + j0 + jj) * HDIM + k8;
            vh = *(const short8*)(whh_hi + off);
            vl = *(const short8*)(whh_lo + off);
        }
        *(short8*)&Wl[0][row][k8] = vh;
        *(short8*)&Wl[1][row][k8] = vl;
    }

    // per-thread constants: this thread's (b, jj) gate item
    const int gb = tid >> 3, gjj = tid & 7;
    const int gj = j0 + gjj;
    const float bhr = b_hh[gj];
    const float bhz = b_hh[HDIM + gj];
    const float bhn = b_hh[2 * HDIM + gj];

    // running h for this (b,j), from slot 0
    float hloc;
    {
        unsigned long long v = __hip_atomic_load(hs64 + (size_t)(gj >> 1) * 32 + gb,
                                                 __ATOMIC_RELAXED, __HIP_MEMORY_SCOPE_AGENT);
        unsigned hwd = (unsigned)v, lwd = (unsigned)(v >> 32);
        unsigned short hi = (gj & 1) ? (unsigned short)(hwd >> 16) : (unsigned short)(hwd & 0xffff);
        unsigned short lo = (gj & 1) ? (unsigned short)(lwd >> 16) : (unsigned short)(lwd & 0xffff);
        hloc = bf2f(hi) + bf2f(lo);
    }
    __syncthreads();

    for (int t = 0; t < T_STEPS; ++t) {
        const size_t tb = (size_t)t * HS_T_STRIDE;

        // gi for this step (normal cached loads)
        const float* girow = gi + (size_t)(t * BATCH + gb) * (3 * HDIM);
        float xr = girow[gj], xz = girow[HDIM + gj], xn = girow[2 * HDIM + gj];

        // ---- counter-hinted wait for all 128 producers of h(t) ----
        if (t) {
            if (wid == 0) {
                while (__hip_atomic_load(cnt + t, __ATOMIC_RELAXED, __HIP_MEMORY_SCOPE_AGENT)
                       < (unsigned)GRU_BLOCKS)
                    __builtin_amdgcn_s_sleep(2);
            }
            __syncthreads();
            asm volatile("" ::: "memory");   // keep the burst below the wait
        }

        // ---- single plain-b64 burst (coalesced; first cached touch of these lines) ----
        unsigned long long wv[8][8];
#pragma unroll
        for (int ks = 0; ks < 8; ++ks) {
            const int wbase = wid * 128 + ks * 16 + kg * 4;   // k-pair index
#pragma unroll
            for (int mi = 0; mi < 2; ++mi) {
                const int b = mi * 16 + l15;
#pragma unroll
                for (int q = 0; q < 4; ++q)
                    wv[ks][mi * 4 + q] = *(const unsigned long long*)(
                        hs64 + tb + (size_t)(wbase + q) * 32 + b);
            }
        }
        // ---- sentinel backstop: parallel retry rounds with cache-bypassing atomics ----
        for (;;) {
            int bad = 0;
#pragma unroll
            for (int ks = 0; ks < 8; ++ks)
#pragma unroll
                for (int i = 0; i < 8; ++i)
                    bad |= ((unsigned)wv[ks][i] == SENT);
            if (!__any(bad)) break;
            __builtin_amdgcn_s_sleep(1);
#pragma unroll
            for (int ks = 0; ks < 8; ++ks)
#pragma unroll
                for (int i = 0; i < 8; ++i)
                    if ((unsigned)wv[ks][i] == SENT) {
                        const int mi = i >> 2, q = i & 3;
                        wv[ks][i] = __hip_atomic_load(
                            hs64 + tb + (size_t)(wid * 128 + ks * 16 + kg * 4 + q) * 32 + (mi * 16 + l15),
                            __ATOMIC_RELAXED, __HIP_MEMORY_SCOPE_AGENT);
                    }
        }

        // MFMA: acc[mi][fr] over 8 K-slices, bf16x3
        f32x4 acc[2][2] = {};
#pragma unroll
        for (int ks = 0; ks < 8; ++ks) {
            const int kb = kq + ks * 32 + kg * 8;
            union U8 { unsigned u[4]; short8 s; };
            short8 ah[2], al[2];
#pragma unroll
            for (int mi = 0; mi < 2; ++mi) {
                U8 x, y;
#pragma unroll
                for (int q = 0; q < 4; ++q) {
                    x.u[q] = (unsigned)wv[ks][mi * 4 + q];
                    y.u[q] = (unsigned)(wv[ks][mi * 4 + q] >> 32);
                }
                ah[mi] = x.s; al[mi] = y.s;
            }
#pragma unroll
            for (int fr = 0; fr < 2; ++fr) {
                short8 bhi = *(const short8*)&Wl[0][fr * 16 + l15][kb];
                short8 blo = *(const short8*)&Wl[1][fr * 16 + l15][kb];
#pragma unroll
                for (int mi = 0; mi < 2; ++mi) {
                    acc[mi][fr] = __builtin_amdgcn_mfma_f32_16x16x32_bf16(ah[mi], bhi, acc[mi][fr], 0, 0, 0);
                    acc[mi][fr] = __builtin_amdgcn_mfma_f32_16x16x32_bf16(ah[mi], blo, acc[mi][fr], 0, 0, 0);
                    acc[mi][fr] = __builtin_amdgcn_mfma_f32_16x16x32_bf16(al[mi], bhi, acc[mi][fr], 0, 0, 0);
                }
            }
        }

        // scatter partials: C/D map col(l15)=W-row, row(kg*4+q)=batch
#pragma unroll
        for (int mi = 0; mi < 2; ++mi)
#pragma unroll
            for (int fr = 0; fr < 2; ++fr)
                if (fr == 0 || l15 < 8)
#pragma unroll
                    for (int q = 0; q < 4; ++q)
                        P[wid][mi * 16 + kg * 4 + q][fr * 16 + l15] = acc[mi][fr][q];
        __syncthreads();

        // gates + immediate publish (shfl pack, no LDS round-trip)
        {
            float ghr = 0.f, ghz = 0.f, ghn = 0.f;
#pragma unroll
            for (int w = 0; w < 4; ++w) {
                ghr += P[w][gb][gjj];
                ghz += P[w][gb][8 + gjj];
                ghn += P[w][gb][16 + gjj];
            }
            float r = 1.f / (1.f + __expf(-(xr + ghr + bhr)));
            float z = 1.f / (1.f + __expf(-(xz + ghz + bhz)));
            float n = tanhf(xn + r * (ghn + bhn));
            float hnew = (1.f - z) * n + z * hloc;
            hloc = hnew;
            unsigned hv = f2bf(hnew);
            unsigned lv = f2bf(hnew - bf2f((unsigned short)hv));
            unsigned hnb = (unsigned)__shfl_xor((int)hv, 1);
            unsigned lnb = (unsigned)__shfl_xor((int)lv, 1);
            if (!(gjj & 1)) {
                unsigned hw = hv | (hnb << 16);
                unsigned lw = lv | (lnb << 16);
                const int wdx = gj >> 1;
                __hip_atomic_store(hs64 + (size_t)(t + 1) * HS_T_STRIDE + (size_t)wdx * 32 + gb,
                                   (unsigned long long)hw | ((unsigned long long)lw << 32),
                                   __ATOMIC_RELAXED, __HIP_MEMORY_SCOPE_AGENT);
                // row-major bf16-hi copy for the scores GEMM (kernel-boundary flush)
                hrow32[((size_t)t * BATCH + gb) * 512 + wdx] = hw;
            }
        }

        // drain all publish stores (s_waitcnt vmcnt(0) before s_barrier), then
        // announce this block's completion of step t. Also protects P reuse.
        __syncthreads();
        if (tid == 0)
            __hip_atomic_fetch_add(cnt + t + 1, 1u, __ATOMIC_RELAXED, __HIP_MEMORY_SCOPE_AGENT);
    }
}

extern "C" void kernel_launch(void* const* d_in, const int* in_sizes, int n_in,
                              void* d_out, int out_size, void* d_ws, size_t ws_size,
                              hipStream_t stream) {
    const float* h0    = (const float*)d_in[0];
    const int*   tseq  = (const int*)d_in[1];
    const float* emb   = (const float*)d_in[2];
    const float* w_ih  = (const float*)d_in[3];
    const float* w_hh  = (const float*)d_in[4];
    const float* b_ih  = (const float*)d_in[5];
    const float* b_hh  = (const float*)d_in[6];
    const float* w_cls = (const float*)d_in[7];
    const float* b_cls = (const float*)d_in[8];
    float* out = (float*)d_out;

    char* w = (char*)d_ws;
    unsigned short* wcls_bf = (unsigned short*)w; w += (size_t)VOCAB * HDIM * 2;
    unsigned short* wih_bf  = (unsigned short*)w; w += (size_t)3 * HDIM * EDIM * 2;
    unsigned short* whh_hi  = (unsigned short*)w; w += (size_t)3 * HDIM * HDIM * 2;
    unsigned short* whh_lo  = (unsigned short*)w; w += (size_t)3 * HDIM * HDIM * 2;
    unsigned short* x_bf    = (unsigned short*)w; w += (size_t)T_STEPS * BATCH * EDIM * 2;
    unsigned long long* hs64 = (unsigned long long*)w; w += (size_t)(T_STEPS + 1) * HS_T_STRIDE * 8;
    unsigned int* hrow32    = (unsigned int*)w;   w += (size_t)T_STEPS * BATCH * 512 * 4;
    float* gi               = (float*)w;          w += (size_t)T_STEPS * BATCH * 3 * HDIM * 4;
    unsigned int* cnt       = (unsigned int*)w;   w += 256;

    prep_kernel<<<2048, 256, 0, stream>>>(h0, tseq, emb, w_ih, w_hh, w_cls,
                                          wcls_bf, wih_bf, whh_hi, whh_lo,
                                          x_bf, hs64, cnt);

    // GI = X @ W_ih^T + b_ih : M=1536, N=3072, K=512  (288 wgs, %8==0)
    gemm_lds<false><<<(T_STEPS * BATCH / 128) * (3 * HDIM / 128), 256, 0, stream>>>(
        x_bf, wih_bf, b_ih, gi, EDIM, 3 * HDIM, T_STEPS * BATCH / 128);

    // all 48 GRU steps: counter-hinted dataflow + sentinel backstop
    gru_persist<<<GRU_BLOCKS, 256, 0, stream>>>(hs64, hrow32, whh_hi, whh_lo, gi, b_hh, cnt);

    // scores = Hrow @ W_cls^T + b_cls : M=1536, N=32000, K=1024 (3000 wgs, %8==0)
    gemm_lds<true><<<(T_STEPS * BATCH / 128) * (VOCAB / 128), 256, 0, stream>>>(
        (const unsigned short*)hrow32, wcls_bf, b_cls, out, HDIM, VOCAB, T_STEPS * BATCH / 128);
}

// Round 11
// 422.742 us; speedup vs baseline: 2.9278x; 1.2688x over previous
//
#include <hip/hip_runtime.h>
#include <hip/hip_bf16.h>

typedef __attribute__((ext_vector_type(8))) short short8;
typedef __attribute__((ext_vector_type(4))) float f32x4;

#define T_STEPS 48
#define BATCH 32
#define EDIM 512
#define HDIM 1024
#define VOCAB 32000
#define GRU_BLOCKS 64
#define JPB 16
#define SENT 0x7FFF7FFFu

// packed h storage (hi-plane only): uint words, [t(49)][k_pair(512)][b(32)]
#define HS_T_STRIDE 16384          // uints per t-slot

__device__ __forceinline__ unsigned short f2bf(float f) {
    __hip_bfloat16 h = __float2bfloat16(f);
    return *reinterpret_cast<unsigned short*>(&h);
}
__device__ __forceinline__ float bf2f(unsigned short u) {
    union { unsigned int i; float f; } v;
    v.i = ((unsigned int)u) << 16;
    return v.f;
}

typedef __attribute__((address_space(1))) const void GAS;
typedef __attribute__((address_space(3))) void LAS;
__device__ __forceinline__ void gload_lds16(const unsigned short* g, unsigned short* l) {
    __builtin_amdgcn_global_load_lds((GAS*)g, (LAS*)(unsigned)(uintptr_t)l, 16, 0, 0);
}

// ---------------- prep: conversions, gather, h0 pack, sentinel fill, cnt zero ----------------
__global__ __launch_bounds__(256) void prep_kernel(
    const float* __restrict__ h0, const int* __restrict__ tseq,
    const float* __restrict__ emb, const float* __restrict__ w_ih,
    const float* __restrict__ w_hh, const float* __restrict__ w_cls,
    unsigned short* __restrict__ wcls_bf, unsigned short* __restrict__ wih_bf,
    unsigned short* __restrict__ whh_bf, unsigned short* __restrict__ x_bf,
    unsigned int* __restrict__ hs32, unsigned int* __restrict__ cnt)
{
    const long R0 = (long)VOCAB * HDIM / 4;           // w_cls
    const long R1 = (long)3 * HDIM * EDIM / 4;        // w_ih
    const long R2 = (long)3 * HDIM * HDIM / 4;        // w_hh (hi only)
    const long R3 = (long)T_STEPS * BATCH * EDIM / 4; // X gather
    const long R4 = (long)HS_T_STRIDE;                // h0 -> packed slot 0
    const long R5 = (long)T_STEPS * HS_T_STRIDE / 4;  // sentinel fill t=1..48 (uint4)
    const long R6 = 16;                               // cnt zero
    const long total = R0 + R1 + R2 + R3 + R4 + R5 + R6;

    for (long i = (long)blockIdx.x * blockDim.x + threadIdx.x; i < total;
         i += (long)gridDim.x * blockDim.x) {
        if (i < R0) {
            float4 v = reinterpret_cast<const float4*>(w_cls)[i];
            ushort4 u = { f2bf(v.x), f2bf(v.y), f2bf(v.z), f2bf(v.w) };
            *reinterpret_cast<ushort4*>(wcls_bf + i * 4) = u;
        } else if (i < R0 + R1) {
            long j = i - R0;
            float4 v = reinterpret_cast<const float4*>(w_ih)[j];
            ushort4 u = { f2bf(v.x), f2bf(v.y), f2bf(v.z), f2bf(v.w) };
            *reinterpret_cast<ushort4*>(wih_bf + j * 4) = u;
        } else if (i < R0 + R1 + R2) {
            long j = i - R0 - R1;
            float4 v = reinterpret_cast<const float4*>(w_hh)[j];
            ushort4 u = { f2bf(v.x), f2bf(v.y), f2bf(v.z), f2bf(v.w) };
            *reinterpret_cast<ushort4*>(whh_bf + j * 4) = u;
        } else if (i < R0 + R1 + R2 + R3) {
            long j = i - R0 - R1 - R2;
            int m = (int)(j >> 7);
            int kk4 = (int)(j & 127);
            int t = m >> 5, b = m & 31;
            int tok = tseq[b * T_STEPS + t];
            float4 v = reinterpret_cast<const float4*>(emb)[(long)tok * (EDIM / 4) + kk4];
            ushort4 u = { f2bf(v.x), f2bf(v.y), f2bf(v.z), f2bf(v.w) };
            *reinterpret_cast<ushort4*>(x_bf + (long)m * EDIM + kk4 * 4) = u;
        } else if (i < R0 + R1 + R2 + R3 + R4) {
            long j = i - R0 - R1 - R2 - R3;       // uint index: w*32 + b
            int w = (int)(j >> 5), b = (int)(j & 31);
            unsigned short a = f2bf(h0[b * HDIM + 2 * w]);
            unsigned short c = f2bf(h0[b * HDIM + 2 * w + 1]);
            hs32[j] = (unsigned)a | ((unsigned)c << 16);
        } else if (i < R0 + R1 + R2 + R3 + R4 + R5) {
            long j = i - R0 - R1 - R2 - R3 - R4;
            uint4 s = { SENT, SENT, SENT, SENT };
            reinterpret_cast<uint4*>(hs32 + HS_T_STRIDE)[j] = s;   // t=1..48
        } else {
            long j = i - R0 - R1 - R2 - R3 - R4 - R5;
            uint4 z = { 0u, 0u, 0u, 0u };
            reinterpret_cast<uint4*>(cnt)[j] = z;
        }
    }
}

// ---------------- bf16 MFMA GEMM (gload_lds staging, XCD swizzle) ----------------
template <bool SCORES>
__global__ __launch_bounds__(256) void gemm_lds(
    const unsigned short* __restrict__ A, const unsigned short* __restrict__ B,
    const float* __restrict__ bias, float* __restrict__ C, int K, int Ntot, int nM)
{
    const int nwg = gridDim.x;
    const int lin = blockIdx.x;
    const int q = nwg >> 3;
    const int wg = (lin & 7) * q + (lin >> 3);
    const int mi = wg % nM, ni = wg / nM;
    const int m0 = mi * 128, n0 = ni * 128;

    const int tid = threadIdx.x;
    const int lane = tid & 63;
    const int wid = tid >> 6;
    const int wr = wid >> 1, wc = wid & 1;

    __shared__ __align__(16) unsigned short As[128 * 32];
    __shared__ __align__(16) unsigned short Bs[128 * 32];

    f32x4 acc[4][4] = {};
    const int NT = K >> 5;
    const int srow = (lane >> 2);
    const int skk = (lane & 3) * 8;

    for (int kt = 0; kt < NT; ++kt) {
        __syncthreads();
        {
            const int kb = kt * 32;
#pragma unroll
            for (int h2 = 0; h2 < 2; ++h2) {
                const int i = wid + h2 * 4;
                const int row = i * 16 + srow;
                gload_lds16(A + (size_t)(m0 + row) * K + kb + skk, As + i * 512);
                gload_lds16(B + (size_t)(n0 + row) * K + kb + skk, Bs + i * 512);
            }
        }
        __syncthreads();

        const int kg = lane >> 4;
        const int l15 = lane & 15;
        short8 af[4], bf[4];
#pragma unroll
        for (int i = 0; i < 4; ++i) {
            af[i] = *(const short8*)(As + ((wr * 64 + i * 16 + l15) * 32 + kg * 8));
            bf[i] = *(const short8*)(Bs + ((wc * 64 + i * 16 + l15) * 32 + kg * 8));
        }
#pragma unroll
        for (int i = 0; i < 4; ++i)
#pragma unroll
            for (int j = 0; j < 4; ++j)
                acc[i][j] = __builtin_amdgcn_mfma_f32_16x16x32_bf16(af[i], bf[j], acc[i][j], 0, 0, 0);
    }

    const int l15 = lane & 15, lhi = lane >> 4;
#pragma unroll
    for (int i = 0; i < 4; ++i) {
#pragma unroll
        for (int j = 0; j < 4; ++j) {
            int col = n0 + wc * 64 + j * 16 + l15;
            float bv = bias[col];
#pragma unroll
            for (int q2 = 0; q2 < 4; ++q2) {
                int row = m0 + wr * 64 + i * 16 + lhi * 4 + q2;
                float v = acc[i][j][q2] + bv;
                if (SCORES) {
                    int t = row >> 5, b = row & 31;
                    C[(size_t)(b * T_STEPS + t) * Ntot + col] = v;
                } else {
                    C[(size_t)row * Ntot + col] = v;
                }
            }
        }
    }
}

// ---------------- persistent GRU: 64 blocks x JPB=16, hi-plane-only exchange ----------------
// W_hh (plain bf16) in LDS: 48 rows x 1024. Counter-hinted single burst (4MB/step
// chip-wide) + sentinel backstop. Running h stays fp32 in registers.
__global__ __launch_bounds__(256, 1) void gru_persist(
    unsigned int* __restrict__ hs32, unsigned int* __restrict__ hrow32,
    const unsigned short* __restrict__ whh_bf,
    const float* __restrict__ gi, const float* __restrict__ b_hh,
    const float* __restrict__ h0, unsigned int* __restrict__ cnt)
{
    const int j0 = blockIdx.x * JPB;
    const int tid = threadIdx.x;
    const int lane = tid & 63, wid = tid >> 6;     // 4 waves
    const int l15 = lane & 15, kg = lane >> 4;     // kg 0..3
    const int kq = wid * 256;                      // wave's K-chunk (bf16 units)

    __shared__ __align__(16) unsigned short Wl[48][1032];  // ~97KB, padded stride
    __shared__ float P[4][32][49];

    // one-time W fill (normal cached loads): row = g*16 + jj
    for (int c = tid; c < 48 * 128; c += 256) {
        int row = c >> 7, k8 = (c & 127) * 8;
        int g = row >> 4, jj = row & 15;
        *(short8*)&Wl[row][k8] =
            *(const short8*)(whh_bf + (size_t)(g * HDIM + j0 + jj) * HDIM + k8);
    }

    // per-thread gate items: (b1, gjj) and (b1+16, gjj)
    const int b1 = tid >> 4, gjj = tid & 15;
    const int gj = j0 + gjj;
    const float bhr = b_hh[gj];
    const float bhz = b_hh[HDIM + gj];
    const float bhn = b_hh[2 * HDIM + gj];

    // running h in fp32 registers (never quantized on the recurrent path)
    float hloc1 = h0[b1 * HDIM + gj];
    float hloc2 = h0[(b1 + 16) * HDIM + gj];
    __syncthreads();

    for (int t = 0; t < T_STEPS; ++t) {
        const size_t tb = (size_t)t * HS_T_STRIDE;

        // gi for this step
        const float* gr1 = gi + (size_t)(t * BATCH + b1) * (3 * HDIM);
        const float* gr2 = gi + (size_t)(t * BATCH + b1 + 16) * (3 * HDIM);
        float xr1 = gr1[gj], xz1 = gr1[HDIM + gj], xn1 = gr1[2 * HDIM + gj];
        float xr2 = gr2[gj], xz2 = gr2[HDIM + gj], xn2 = gr2[2 * HDIM + gj];

        // ---- counter-hinted wait for all 64 producers of h(t) ----
        if (t) {
            if (wid == 0) {
                while (__hip_atomic_load(cnt + t, __ATOMIC_RELAXED, __HIP_MEMORY_SCOPE_AGENT)
                       < (unsigned)GRU_BLOCKS)
                    __builtin_amdgcn_s_sleep(2);
            }
            __syncthreads();
            asm volatile("" ::: "memory");
        }

        // ---- single plain burst: 64 coalesced b32 loads (hi-plane only) ----
        unsigned wv[8][8];
#pragma unroll
        for (int ks = 0; ks < 8; ++ks) {
            const int wbase = wid * 128 + ks * 16 + kg * 4;   // k-pair index
#pragma unroll
            for (int mi = 0; mi < 2; ++mi) {
                const int b = mi * 16 + l15;
#pragma unroll
                for (int q = 0; q < 4; ++q)
                    wv[ks][mi * 4 + q] = *(const unsigned*)(
                        hs32 + tb + (size_t)(wbase + q) * 32 + b);
            }
        }
        // ---- sentinel backstop: parallel retry rounds, cache-bypassing atomics ----
        for (;;) {
            int bad = 0;
#pragma unroll
            for (int ks = 0; ks < 8; ++ks)
#pragma unroll
                for (int i = 0; i < 8; ++i)
                    bad |= (wv[ks][i] == SENT);
            if (!__any(bad)) break;
            __builtin_amdgcn_s_sleep(1);
#pragma unroll
            for (int ks = 0; ks < 8; ++ks)
#pragma unroll
                for (int i = 0; i < 8; ++i)
                    if (wv[ks][i] == SENT) {
                        const int mi = i >> 2, q = i & 3;
                        wv[ks][i] = __hip_atomic_load(
                            hs32 + tb + (size_t)(wid * 128 + ks * 16 + kg * 4 + q) * 32 + (mi * 16 + l15),
                            __ATOMIC_RELAXED, __HIP_MEMORY_SCOPE_AGENT);
                    }
        }

        // MFMA: acc[mi][fr], 8 K-slices, plain bf16
        f32x4 acc[2][3] = {};
#pragma unroll
        for (int ks = 0; ks < 8; ++ks) {
            const int kb = kq + ks * 32 + kg * 8;
            union U8 { unsigned u[4]; short8 s; };
            short8 ah[2];
#pragma unroll
            for (int mi = 0; mi < 2; ++mi) {
                U8 x;
#pragma unroll
                for (int q = 0; q < 4; ++q) x.u[q] = wv[ks][mi * 4 + q];
                ah[mi] = x.s;
            }
#pragma unroll
            for (int fr = 0; fr < 3; ++fr) {
                short8 bh = *(const short8*)&Wl[fr * 16 + l15][kb];
#pragma unroll
                for (int mi = 0; mi < 2; ++mi)
                    acc[mi][fr] = __builtin_amdgcn_mfma_f32_16x16x32_bf16(ah[mi], bh, acc[mi][fr], 0, 0, 0);
            }
        }

        // scatter partials: C/D map col(l15)=W-row(fr*16+l15), row(kg*4+q)=batch
#pragma unroll
        for (int mi = 0; mi < 2; ++mi)
#pragma unroll
            for (int fr = 0; fr < 3; ++fr)
#pragma unroll
                for (int q = 0; q < 4; ++q)
                    P[wid][mi * 16 + kg * 4 + q][fr * 16 + l15] = acc[mi][fr][q];
        __syncthreads();

        // gates for both items + publish (shfl pack)
        {
            float ghr1 = 0.f, ghz1 = 0.f, ghn1 = 0.f;
            float ghr2 = 0.f, ghz2 = 0.f, ghn2 = 0.f;
#pragma unroll
            for (int w = 0; w < 4; ++w) {
                ghr1 += P[w][b1][gjj];       ghr2 += P[w][b1 + 16][gjj];
                ghz1 += P[w][b1][16 + gjj];  ghz2 += P[w][b1 + 16][16 + gjj];
                ghn1 += P[w][b1][32 + gjj];  ghn2 += P[w][b1 + 16][32 + gjj];
            }
            float r1 = 1.f / (1.f + __expf(-(xr1 + ghr1 + bhr)));
            float z1 = 1.f / (1.f + __expf(-(xz1 + ghz1 + bhz)));
            float n1 = tanhf(xn1 + r1 * (ghn1 + bhn));
            float hn1 = (1.f - z1) * n1 + z1 * hloc1;
            float r2 = 1.f / (1.f + __expf(-(xr2 + ghr2 + bhr)));
            float z2 = 1.f / (1.f + __expf(-(xz2 + ghz2 + bhz)));
            float n2 = tanhf(xn2 + r2 * (ghn2 + bhn));
            float hn2 = (1.f - z2) * n2 + z2 * hloc2;
            hloc1 = hn1; hloc2 = hn2;
            unsigned hv1 = f2bf(hn1), hv2 = f2bf(hn2);
            unsigned nb1 = (unsigned)__shfl_xor((int)hv1, 1);
            unsigned nb2 = (unsigned)__shfl_xor((int)hv2, 1);
            if (!(gjj & 1)) {
                unsigned w1 = hv1 | (nb1 << 16);
                unsigned w2 = hv2 | (nb2 << 16);
                const int wdx = gj >> 1;
                const size_t o = (size_t)(t + 1) * HS_T_STRIDE + (size_t)wdx * 32;
                __hip_atomic_store(hs32 + o + b1, w1, __ATOMIC_RELAXED, __HIP_MEMORY_SCOPE_AGENT);
                __hip_atomic_store(hs32 + o + b1 + 16, w2, __ATOMIC_RELAXED, __HIP_MEMORY_SCOPE_AGENT);
                hrow32[((size_t)t * BATCH + b1) * 512 + wdx] = w1;
                hrow32[((size_t)t * BATCH + b1 + 16) * 512 + wdx] = w2;
            }
        }

        // drain publish stores (vmcnt(0) before s_barrier), then announce step t done.
        __syncthreads();
        if (tid == 0)
            __hip_atomic_fetch_add(cnt + t + 1, 1u, __ATOMIC_RELAXED, __HIP_MEMORY_SCOPE_AGENT);
    }
}

extern "C" void kernel_launch(void* const* d_in, const int* in_sizes, int n_in,
                              void* d_out, int out_size, void* d_ws, size_t ws_size,
                              hipStream_t stream) {
    const float* h0    = (const float*)d_in[0];
    const int*   tseq  = (const int*)d_in[1];
    const float* emb   = (const float*)d_in[2];
    const float* w_ih  = (const float*)d_in[3];
    const float* w_hh  = (const float*)d_in[4];
    const float* b_ih  = (const float*)d_in[5];
    const float* b_hh  = (const float*)d_in[6];
    const float* w_cls = (const float*)d_in[7];
    const float* b_cls = (const float*)d_in[8];
    float* out = (float*)d_out;

    char* w = (char*)d_ws;
    unsigned short* wcls_bf = (unsigned short*)w; w += (size_t)VOCAB * HDIM * 2;
    unsigned short* wih_bf  = (unsigned short*)w; w += (size_t)3 * HDIM * EDIM * 2;
    unsigned short* whh_bf  = (unsigned short*)w; w += (size_t)3 * HDIM * HDIM * 2;
    unsigned short* x_bf    = (unsigned short*)w; w += (size_t)T_STEPS * BATCH * EDIM * 2;
    unsigned int*   hs32    = (unsigned int*)w;   w += (size_t)(T_STEPS + 1) * HS_T_STRIDE * 4;
    unsigned int*   hrow32  = (unsigned int*)w;   w += (size_t)T_STEPS * BATCH * 512 * 4;
    float* gi               = (float*)w;          w += (size_t)T_STEPS * BATCH * 3 * HDIM * 4;
    unsigned int* cnt       = (unsigned int*)w;   w += 256;

    prep_kernel<<<2048, 256, 0, stream>>>(h0, tseq, emb, w_ih, w_hh, w_cls,
                                          wcls_bf, wih_bf, whh_bf, x_bf, hs32, cnt);

    // GI = X @ W_ih^T + b_ih : M=1536, N=3072, K=512  (288 wgs, %8==0)
    gemm_lds<false><<<(T_STEPS * BATCH / 128) * (3 * HDIM / 128), 256, 0, stream>>>(
        x_bf, wih_bf, b_ih, gi, EDIM, 3 * HDIM, T_STEPS * BATCH / 128);

    // all 48 GRU steps: 64-block counter-hinted dataflow + sentinel backstop
    gru_persist<<<GRU_BLOCKS, 256, 0, stream>>>(hs32, hrow32, whh_bf, gi, b_hh, h0, cnt);

    // scores = Hrow @ W_cls^T + b_cls : M=1536, N=32000, K=1024 (3000 wgs, %8==0)
    gemm_lds<true><<<(T_STEPS * BATCH / 128) * (VOCAB / 128), 256, 0, stream>>>(
        (const unsigned short*)hrow32, wcls_bf, b_cls, out, HDIM, VOCAB, T_STEPS * BATCH / 128);
}

// Round 13
// 405.987 us; speedup vs baseline: 3.0487x; 1.0413x over previous
//
#include <hip/hip_runtime.h>
#include <hip/hip_bf16.h>

typedef __attribute__((ext_vector_type(8))) short short8;
typedef __attribute__((ext_vector_type(4))) float f32x4;

#define T_STEPS 48
#define BATCH 32
#define EDIM 512
#define HDIM 1024
#define VOCAB 32000
#define GRU_BLOCKS 64
#define JPB 16
#define SENT 0x7FFF7FFFu

// packed h storage (hi-plane only): uint words, [t(49)][k_pair(512)][b(32)]
#define HS_T_STRIDE 16384          // uints per t-slot

__device__ __forceinline__ unsigned short f2bf(float f) {
    __hip_bfloat16 h = __float2bfloat16(f);
    return *reinterpret_cast<unsigned short*>(&h);
}
__device__ __forceinline__ float bf2f(unsigned short u) {
    union { unsigned int i; float f; } v;
    v.i = ((unsigned int)u) << 16;
    return v.f;
}

typedef __attribute__((address_space(1))) const void GAS;
typedef __attribute__((address_space(3))) void LAS;
__device__ __forceinline__ void gload_lds16(const unsigned short* g, unsigned short* l) {
    __builtin_amdgcn_global_load_lds((GAS*)g, (LAS*)(unsigned)(uintptr_t)l, 16, 0, 0);
}

// ---------------- prep: conversions, gather, h0 pack, sentinel fill, cnt zero ----------------
__global__ __launch_bounds__(256) void prep_kernel(
    const float* __restrict__ h0, const int* __restrict__ tseq,
    const float* __restrict__ emb, const float* __restrict__ w_ih,
    const float* __restrict__ w_hh, const float* __restrict__ w_cls,
    unsigned short* __restrict__ wcls_bf, unsigned short* __restrict__ wih_bf,
    unsigned short* __restrict__ whh_bf, unsigned short* __restrict__ x_bf,
    unsigned int* __restrict__ hs32, unsigned int* __restrict__ cnt8)
{
    const long R0 = (long)VOCAB * HDIM / 4;           // w_cls
    const long R1 = (long)3 * HDIM * EDIM / 4;        // w_ih
    const long R2 = (long)3 * HDIM * HDIM / 4;        // w_hh (hi only)
    const long R3 = (long)T_STEPS * BATCH * EDIM / 4; // X gather
    const long R4 = (long)HS_T_STRIDE;                // h0 -> packed slot 0
    const long R5 = (long)T_STEPS * HS_T_STRIDE / 4;  // sentinel fill t=1..48 (uint4)
    const long R6 = ((long)(T_STEPS + 1) * 8) / 4;    // cnt8 zero (98 x uint4)
    const long total = R0 + R1 + R2 + R3 + R4 + R5 + R6;

    for (long i = (long)blockIdx.x * blockDim.x + threadIdx.x; i < total;
         i += (long)gridDim.x * blockDim.x) {
        if (i < R0) {
            float4 v = reinterpret_cast<const float4*>(w_cls)[i];
            ushort4 u = { f2bf(v.x), f2bf(v.y), f2bf(v.z), f2bf(v.w) };
            *reinterpret_cast<ushort4*>(wcls_bf + i * 4) = u;
        } else if (i < R0 + R1) {
            long j = i - R0;
            float4 v = reinterpret_cast<const float4*>(w_ih)[j];
            ushort4 u = { f2bf(v.x), f2bf(v.y), f2bf(v.z), f2bf(v.w) };
            *reinterpret_cast<ushort4*>(wih_bf + j * 4) = u;
        } else if (i < R0 + R1 + R2) {
            long j = i - R0 - R1;
            float4 v = reinterpret_cast<const float4*>(w_hh)[j];
            ushort4 u = { f2bf(v.x), f2bf(v.y), f2bf(v.z), f2bf(v.w) };
            *reinterpret_cast<ushort4*>(whh_bf + j * 4) = u;
        } else if (i < R0 + R1 + R2 + R3) {
            long j = i - R0 - R1 - R2;
            int m = (int)(j >> 7);
            int kk4 = (int)(j & 127);
            int t = m >> 5, b = m & 31;
            int tok = tseq[b * T_STEPS + t];
            float4 v = reinterpret_cast<const float4*>(emb)[(long)tok * (EDIM / 4) + kk4];
            ushort4 u = { f2bf(v.x), f2bf(v.y), f2bf(v.z), f2bf(v.w) };
            *reinterpret_cast<ushort4*>(x_bf + (long)m * EDIM + kk4 * 4) = u;
        } else if (i < R0 + R1 + R2 + R3 + R4) {
            long j = i - R0 - R1 - R2 - R3;       // uint index: w*32 + b
            int w = (int)(j >> 5), b = (int)(j & 31);
            unsigned short a = f2bf(h0[b * HDIM + 2 * w]);
            unsigned short c = f2bf(h0[b * HDIM + 2 * w + 1]);
            hs32[j] = (unsigned)a | ((unsigned)c << 16);
        } else if (i < R0 + R1 + R2 + R3 + R4 + R5) {
            long j = i - R0 - R1 - R2 - R3 - R4;
            uint4 s = { SENT, SENT, SENT, SENT };
            reinterpret_cast<uint4*>(hs32 + HS_T_STRIDE)[j] = s;   // t=1..48
        } else {
            long j = i - R0 - R1 - R2 - R3 - R4 - R5;
            uint4 z = { 0u, 0u, 0u, 0u };
            reinterpret_cast<uint4*>(cnt8)[j] = z;
        }
    }
}

// ---------------- bf16 MFMA GEMM (gload_lds staging, XCD swizzle) ----------------
// SCORES=true additionally: C scatter [b][t][V] with NON-TEMPORAL stores (keep the
// 192MB fp32 C stream out of L2 so B panels survive for their 12 consumers).
template <bool SCORES>
__global__ __launch_bounds__(256) void gemm_lds(
    const unsigned short* __restrict__ A, const unsigned short* __restrict__ B,
    const float* __restrict__ bias, float* __restrict__ C, int K, int Ntot, int nM)
{
    const int nwg = gridDim.x;
    const int lin = blockIdx.x;
    const int q = nwg >> 3;
    const int wg = (lin & 7) * q + (lin >> 3);
    const int mi = wg % nM, ni = wg / nM;
    const int m0 = mi * 128, n0 = ni * 128;

    const int tid = threadIdx.x;
    const int lane = tid & 63;
    const int wid = tid >> 6;
    const int wr = wid >> 1, wc = wid & 1;

    __shared__ __align__(16) unsigned short As[128 * 32];
    __shared__ __align__(16) unsigned short Bs[128 * 32];

    f32x4 acc[4][4] = {};
    const int NT = K >> 5;
    const int srow = (lane >> 2);
    const int skk = (lane & 3) * 8;

    for (int kt = 0; kt < NT; ++kt) {
        __syncthreads();
        {
            const int kb = kt * 32;
#pragma unroll
            for (int h2 = 0; h2 < 2; ++h2) {
                const int i = wid + h2 * 4;
                const int row = i * 16 + srow;
                gload_lds16(A + (size_t)(m0 + row) * K + kb + skk, As + i * 512);
                gload_lds16(B + (size_t)(n0 + row) * K + kb + skk, Bs + i * 512);
            }
        }
        __syncthreads();

        const int kg = lane >> 4;
        const int l15 = lane & 15;
        short8 af[4], bf[4];
#pragma unroll
        for (int i = 0; i < 4; ++i) {
            af[i] = *(const short8*)(As + ((wr * 64 + i * 16 + l15) * 32 + kg * 8));
            bf[i] = *(const short8*)(Bs + ((wc * 64 + i * 16 + l15) * 32 + kg * 8));
        }
#pragma unroll
        for (int i = 0; i < 4; ++i)
#pragma unroll
            for (int j = 0; j < 4; ++j)
                acc[i][j] = __builtin_amdgcn_mfma_f32_16x16x32_bf16(af[i], bf[j], acc[i][j], 0, 0, 0);
    }

    const int l15 = lane & 15, lhi = lane >> 4;
#pragma unroll
    for (int i = 0; i < 4; ++i) {
#pragma unroll
        for (int j = 0; j < 4; ++j) {
            int col = n0 + wc * 64 + j * 16 + l15;
            float bv = bias[col];
#pragma unroll
            for (int q2 = 0; q2 < 4; ++q2) {
                int row = m0 + wr * 64 + i * 16 + lhi * 4 + q2;
                float v = acc[i][j][q2] + bv;
                if (SCORES) {
                    int t = row >> 5, b = row & 31;
                    __builtin_nontemporal_store(v, &C[(size_t)(b * T_STEPS + t) * Ntot + col]);
                } else {
                    C[(size_t)row * Ntot + col] = v;
                }
            }
        }
    }
}

// ---------------- persistent GRU: 8-way-split counter hint + sentinel backstop ----------------
// 64 blocks x 256 threads, JPB=16. W_hh in LDS. h exchange [t][k_pair][b]
// (coalesced b32). Producer: publish -> __syncthreads (vmcnt(0) drain) ->
// fetch_add(cnt8[t+1][bid&7]) (8 parallel RMW chains of 8 instead of 64 on one
// line). Consumer: lanes 0-7 of wave0 poll all 8 sub-counters in parallel.
__global__ __launch_bounds__(256, 1) void gru_persist(
    unsigned int* __restrict__ hs32, unsigned int* __restrict__ hrow32,
    const unsigned short* __restrict__ whh_bf,
    const float* __restrict__ gi, const float* __restrict__ b_hh,
    const float* __restrict__ h0, unsigned int* __restrict__ cnt8)
{
    const int j0 = blockIdx.x * JPB;
    const int tid = threadIdx.x;
    const int lane = tid & 63, wid = tid >> 6;     // 4 waves
    const int l15 = lane & 15, kg = lane >> 4;     // kg 0..3
    const int kq = wid * 256;                      // wave's K-chunk (bf16 units)

    __shared__ __align__(16) unsigned short Wl[48][1032];  // ~97KB, padded stride
    __shared__ float P[4][32][49];

    // one-time W fill (normal cached loads): row = g*16 + jj
    for (int c = tid; c < 48 * 128; c += 256) {
        int row = c >> 7, k8 = (c & 127) * 8;
        int g = row >> 4, jj = row & 15;
        *(short8*)&Wl[row][k8] =
            *(const short8*)(whh_bf + (size_t)(g * HDIM + j0 + jj) * HDIM + k8);
    }

    // per-thread gate items: (b1, gjj) and (b1+16, gjj)
    const int b1 = tid >> 4, gjj = tid & 15;
    const int gj = j0 + gjj;
    const float bhr = b_hh[gj];
    const float bhz = b_hh[HDIM + gj];
    const float bhn = b_hh[2 * HDIM + gj];

    // running h in fp32 registers (never quantized on the recurrent path)
    float hloc1 = h0[b1 * HDIM + gj];
    float hloc2 = h0[(b1 + 16) * HDIM + gj];
    __syncthreads();

    for (int t = 0; t < T_STEPS; ++t) {
        const size_t tb = (size_t)t * HS_T_STRIDE;

        // gi for this step
        const float* gr1 = gi + (size_t)(t * BATCH + b1) * (3 * HDIM);
        const float* gr2 = gi + (size_t)(t * BATCH + b1 + 16) * (3 * HDIM);
        float xr1 = gr1[gj], xz1 = gr1[HDIM + gj], xn1 = gr1[2 * HDIM + gj];
        float xr2 = gr2[gj], xz2 = gr2[HDIM + gj], xn2 = gr2[2 * HDIM + gj];

        // ---- counter-hinted wait: 8 sub-counters polled in parallel by lanes 0-7 ----
        if (t) {
            if (wid == 0) {
                const unsigned int* cp = cnt8 + (size_t)t * 8;
                for (;;) {
                    unsigned v = (lane < 8)
                        ? __hip_atomic_load(cp + lane, __ATOMIC_RELAXED, __HIP_MEMORY_SCOPE_AGENT)
                        : 8u;
                    if (__all(v >= 8u)) break;
                    __builtin_amdgcn_s_sleep(2);
                }
            }
            __syncthreads();
            asm volatile("" ::: "memory");
        }

        // ---- single plain burst: 64 coalesced b32 loads (hi-plane only) ----
        unsigned wv[8][8];
#pragma unroll
        for (int ks = 0; ks < 8; ++ks) {
            const int wbase = wid * 128 + ks * 16 + kg * 4;   // k-pair index
#pragma unroll
            for (int mi = 0; mi < 2; ++mi) {
                const int b = mi * 16 + l15;
#pragma unroll
                for (int q = 0; q < 4; ++q)
                    wv[ks][mi * 4 + q] = *(const unsigned*)(
                        hs32 + tb + (size_t)(wbase + q) * 32 + b);
            }
        }
        // ---- sentinel backstop: parallel retry rounds, cache-bypassing atomics ----
        for (;;) {
            int bad = 0;
#pragma unroll
            for (int ks = 0; ks < 8; ++ks)
#pragma unroll
                for (int i = 0; i < 8; ++i)
                    bad |= (wv[ks][i] == SENT);
            if (!__any(bad)) break;
            __builtin_amdgcn_s_sleep(1);
#pragma unroll
            for (int ks = 0; ks < 8; ++ks)
#pragma unroll
                for (int i = 0; i < 8; ++i)
                    if (wv[ks][i] == SENT) {
                        const int mi = i >> 2, q = i & 3;
                        wv[ks][i] = __hip_atomic_load(
                            hs32 + tb + (size_t)(wid * 128 + ks * 16 + kg * 4 + q) * 32 + (mi * 16 + l15),
                            __ATOMIC_RELAXED, __HIP_MEMORY_SCOPE_AGENT);
                    }
        }

        // MFMA: acc[mi][fr], 8 K-slices, plain bf16
        f32x4 acc[2][3] = {};
#pragma unroll
        for (int ks = 0; ks < 8; ++ks) {
            const int kb = kq + ks * 32 + kg * 8;
            union U8 { unsigned u[4]; short8 s; };
            short8 ah[2];
#pragma unroll
            for (int mi = 0; mi < 2; ++mi) {
                U8 x;
#pragma unroll
                for (int q = 0; q < 4; ++q) x.u[q] = wv[ks][mi * 4 + q];
                ah[mi] = x.s;
            }
#pragma unroll
            for (int fr = 0; fr < 3; ++fr) {
                short8 bh = *(const short8*)&Wl[fr * 16 + l15][kb];
#pragma unroll
                for (int mi = 0; mi < 2; ++mi)
                    acc[mi][fr] = __builtin_amdgcn_mfma_f32_16x16x32_bf16(ah[mi], bh, acc[mi][fr], 0, 0, 0);
            }
        }

        // scatter partials: C/D map col(l15)=W-row(fr*16+l15), row(kg*4+q)=batch
#pragma unroll
        for (int mi = 0; mi < 2; ++mi)
#pragma unroll
            for (int fr = 0; fr < 3; ++fr)
#pragma unroll
                for (int q = 0; q < 4; ++q)
                    P[wid][mi * 16 + kg * 4 + q][fr * 16 + l15] = acc[mi][fr][q];
        __syncthreads();

        // gates for both items + publish (shfl pack)
        {
            float ghr1 = 0.f, ghz1 = 0.f, ghn1 = 0.f;
            float ghr2 = 0.f, ghz2 = 0.f, ghn2 = 0.f;
#pragma unroll
            for (int w = 0; w < 4; ++w) {
                ghr1 += P[w][b1][gjj];       ghr2 += P[w][b1 + 16][gjj];
                ghz1 += P[w][b1][16 + gjj];  ghz2 += P[w][b1 + 16][16 + gjj];
                ghn1 += P[w][b1][32 + gjj];  ghn2 += P[w][b1 + 16][32 + gjj];
            }
            float r1 = 1.f / (1.f + __expf(-(xr1 + ghr1 + bhr)));
            float z1 = 1.f / (1.f + __expf(-(xz1 + ghz1 + bhz)));
            float n1 = tanhf(xn1 + r1 * (ghn1 + bhn));
            float hn1 = (1.f - z1) * n1 + z1 * hloc1;
            float r2 = 1.f / (1.f + __expf(-(xr2 + ghr2 + bhr)));
            float z2 = 1.f / (1.f + __expf(-(xz2 + ghz2 + bhz)));
            float n2 = tanhf(xn2 + r2 * (ghn2 + bhn));
            float hn2 = (1.f - z2) * n2 + z2 * hloc2;
            hloc1 = hn1; hloc2 = hn2;
            unsigned hv1 = f2bf(hn1), hv2 = f2bf(hn2);
            unsigned nb1 = (unsigned)__shfl_xor((int)hv1, 1);
            unsigned nb2 = (unsigned)__shfl_xor((int)hv2, 1);
            if (!(gjj & 1)) {
                unsigned w1 = hv1 | (nb1 << 16);
                unsigned w2 = hv2 | (nb2 << 16);
                const int wdx = gj >> 1;
                const size_t o = (size_t)(t + 1) * HS_T_STRIDE + (size_t)wdx * 32;
                __hip_atomic_store(hs32 + o + b1, w1, __ATOMIC_RELAXED, __HIP_MEMORY_SCOPE_AGENT);
                __hip_atomic_store(hs32 + o + b1 + 16, w2, __ATOMIC_RELAXED, __HIP_MEMORY_SCOPE_AGENT);
                hrow32[((size_t)t * BATCH + b1) * 512 + wdx] = w1;
                hrow32[((size_t)t * BATCH + b1 + 16) * 512 + wdx] = w2;
            }
        }

        // drain publish stores (vmcnt(0) before s_barrier), then announce step t done.
        __syncthreads();
        if (tid == 0)
            __hip_atomic_fetch_add(cnt8 + (size_t)(t + 1) * 8 + (blockIdx.x & 7), 1u,
                                   __ATOMIC_RELAXED, __HIP_MEMORY_SCOPE_AGENT);
    }
}

extern "C" void kernel_launch(void* const* d_in, const int* in_sizes, int n_in,
                              void* d_out, int out_size, void* d_ws, size_t ws_size,
                              hipStream_t stream) {
    const float* h0    = (const float*)d_in[0];
    const int*   tseq  = (const int*)d_in[1];
    const float* emb   = (const float*)d_in[2];
    const float* w_ih  = (const float*)d_in[3];
    const float* w_hh  = (const float*)d_in[4];
    const float* b_ih  = (const float*)d_in[5];
    const float* b_hh  = (const float*)d_in[6];
    const float* w_cls = (const float*)d_in[7];
    const float* b_cls = (const float*)d_in[8];
    float* out = (float*)d_out;

    char* w = (char*)d_ws;
    unsigned short* wcls_bf = (unsigned short*)w; w += (size_t)VOCAB * HDIM * 2;
    unsigned short* wih_bf  = (unsigned short*)w; w += (size_t)3 * HDIM * EDIM * 2;
    unsigned short* whh_bf  = (unsigned short*)w; w += (size_t)3 * HDIM * HDIM * 2;
    unsigned short* x_bf    = (unsigned short*)w; w += (size_t)T_STEPS * BATCH * EDIM * 2;
    unsigned int*   hs32    = (unsigned int*)w;   w += (size_t)(T_STEPS + 1) * HS_T_STRIDE * 4;
    unsigned int*   hrow32  = (unsigned int*)w;   w += (size_t)T_STEPS * BATCH * 512 * 4;
    float* gi               = (float*)w;          w += (size_t)T_STEPS * BATCH * 3 * HDIM * 4;
    unsigned int* cnt8      = (unsigned int*)w;   w += 2048;

    prep_kernel<<<2048, 256, 0, stream>>>(h0, tseq, emb, w_ih, w_hh, w_cls,
                                          wcls_bf, wih_bf, whh_bf, x_bf, hs32, cnt8);

    // GI = X @ W_ih^T + b_ih : M=1536, N=3072, K=512  (288 wgs, %8==0)
    gemm_lds<false><<<(T_STEPS * BATCH / 128) * (3 * HDIM / 128), 256, 0, stream>>>(
        x_bf, wih_bf, b_ih, gi, EDIM, 3 * HDIM, T_STEPS * BATCH / 128);

    // all 48 GRU steps: 8-way-split counter hint + sentinel backstop
    gru_persist<<<GRU_BLOCKS, 256, 0, stream>>>(hs32, hrow32, whh_bf, gi, b_hh, h0, cnt8);

    // scores = Hrow @ W_cls^T + b_cls : M=1536, N=32000, K=1024 (3000 wgs, %8==0)
    gemm_lds<true><<<(T_STEPS * BATCH / 128) * (VOCAB / 128), 256, 0, stream>>>(
        (const unsigned short*)hrow32, wcls_bf, b_cls, out, HDIM, VOCAB, T_STEPS * BATCH / 128);
}